// Round 12
// baseline (458.661 us; speedup 1.0000x reference)
//
#include <hip/hip_runtime.h>
#include <hip/hip_cooperative_groups.h>
#include <hip/hip_fp16.h>
#include <math.h>

#define B_N 2048
#define F_N 512
#define H_N 256
#define E_N 64

typedef __attribute__((ext_vector_type(8))) _Float16 half8;
typedef __attribute__((ext_vector_type(4))) float f32x4;

#define GLL(srcp, dstp)                                                       \
  __builtin_amdgcn_global_load_lds(                                           \
      (const __attribute__((address_space(1))) void*)(srcp),                  \
      (__attribute__((address_space(3))) void*)(dstp), 16, 0, 0)

// ================= MEGA KERNEL (cooperative, 512 x 256) =====================
struct MegaArgs {
  const float* features; const float* proj_w; const float* proj_b;
  const float* expert_emb; const float* expert_features; const float* trust;
  const float* dt; const float* fst_w; const float* fst_b;
  float* out;
  float* pwT; float* embT; float* enT; float* coef; float* gbias;
  float* fnorm; float* scores8; float* selw; float* wlist; float* ypart;
  int* cnt; int* njobs; int* jobs; int* tlist; int* sel;
  _Float16* Fh; _Float16* Fl; _Float16* GhT; _Float16* GlT; _Float16* WhT;
};

__global__ __launch_bounds__(256, 2) void k_mega(MegaArgs a) {
  __shared__ __align__(16) float shmF[16768];  // 67072 B union buffer
  cooperative_groups::grid_group grid = cooperative_groups::this_grid();
  int bid = blockIdx.x, tid = threadIdx.x;
  int wave = tid >> 6, lane = tid & 63;

  // ---------------- P1: prep (2112 virtual blocks) --------------------------
  for (int vb = bid; vb < 2112; vb += 512) {
    __syncthreads();  // protect shm reuse across iterations
    if (vb < 512) {
      int idx = vb * 256 + tid;
      int f = idx >> 8, h = idx & 255;
      a.pwT[idx] = a.proj_w[h * 512 + f];
      if (vb == 0 && tid < E_N) a.cnt[tid] = 0;
      if (vb == 0 && tid == 64) a.njobs[0] = 0;
    } else if (vb < 576) {
      float* parts = shmF + 16704;
      int e = vb - 512;
      float v0 = a.expert_features[e * 512 + tid];
      float v1 = a.expert_features[e * 512 + tid + 256];
      float ss = v0 * v0 + v1 * v1;
      #pragma unroll
      for (int off = 32; off; off >>= 1) ss += __shfl_xor(ss, off);
      if ((tid & 63) == 0) parts[tid >> 6] = ss;
      __syncthreads();
      float tot = parts[0] + parts[1] + parts[2] + parts[3];
      float inv = 1.0f / fmaxf(sqrtf(tot), 1e-8f);
      a.enT[tid * 64 + e] = v0 * inv;
      a.enT[(tid + 256) * 64 + e] = v1 * inv;
      a.embT[tid * 64 + e] = a.expert_emb[e * 256 + tid];
      if (tid == 0) {
        float st = fmaxf(0.1f, expf(-0.005f * a.dt[e]));
        a.coef[e] = a.trust[e] * st;
      }
    } else if (vb < 1088) {
      int gid = (vb - 576) * 256 + tid;
      int i = gid * 8;
      float4 v0 = *(const float4*)(a.features + i);
      float4 v1 = *(const float4*)(a.features + i + 4);
      float xs[8] = {v0.x, v0.y, v0.z, v0.w, v1.x, v1.y, v1.z, v1.w};
      half8 h, l;
      float ss = 0.0f;
      #pragma unroll
      for (int j = 0; j < 8; ++j) {
        h[j] = (_Float16)xs[j];
        l[j] = (_Float16)((xs[j] - (float)h[j]) * 2048.0f);
        ss = fmaf(xs[j], xs[j], ss);
      }
      *(half8*)(a.Fh + i) = h;
      *(half8*)(a.Fl + i) = l;
      #pragma unroll
      for (int off = 32; off; off >>= 1) ss += __shfl_xor(ss, off);
      if ((tid & 63) == 0) a.fnorm[gid >> 6] = ss;
    } else {
      float* tile = shmF;
      int b2 = vb - 1088;  // 1024 = 64e x 8kb x 2cb
      int e = b2 >> 4;
      int kb = (b2 >> 1) & 7;
      int cb = b2 & 1;
      const float* src = a.fst_w + ((size_t)e << 18) +
                         (size_t)(kb * 64) * 512 + cb * 256;
      int kr = tid >> 6;
      int c4 = (tid & 63) * 4;
      #pragma unroll
      for (int r = 0; r < 16; ++r) {
        int k = r * 4 + kr;
        *(float4*)&tile[k * 260 + ((k >> 3) << 2) + c4] =
            *(const float4*)&src[(size_t)k * 512 + c4];
      }
      __syncthreads();
      int co = tid >> 3;
      int ko = (tid & 7) * 8;
      #pragma unroll
      for (int g = 0; g < 8; ++g) {
        int c = g * 32 + co;
        half8 vh;
        #pragma unroll
        for (int i = 0; i < 8; ++i) {
          int k = ko + i;
          vh[i] = (_Float16)tile[k * 260 + ((k >> 3) << 2) + c];
        }
        size_t dbase =
            ((size_t)e << 18) + (size_t)(cb * 256 + c) * 512 + kb * 64 + ko;
        *(half8*)(a.WhT + dbase) = vh;
      }
    }
  }
  grid.sync();

  // ---------------- P2: G matrix -> GhT/GlT + gbias (wave = one f) ----------
  {
    int f = bid * 4 + wave;
    bool ok = (f <= 512);
    float* row = shmF + wave * 256;
    if (ok) {
      const float* src = (f < 512) ? (a.pwT + f * 256) : a.proj_b;
      *(float4*)&row[lane * 4] = *(const float4*)&src[lane * 4];
      // same-wave LDS producer/consumer (wave64-coherent)
      float g = 0.0f;
      #pragma unroll 8
      for (int h = 0; h < 256; ++h) g = fmaf(row[h], a.embT[h * 64 + lane], g);
      if (f < 512) {
        _Float16 h0 = (_Float16)g;
        a.GhT[lane * 512 + f] = h0;
        a.GlT[lane * 512 + f] = (_Float16)((g - (float)h0) * 2048.0f);
        float en = a.enT[f * 64 + lane];
        _Float16 h1 = (_Float16)en;
        a.GhT[(64 + lane) * 512 + f] = h1;
        a.GlT[(64 + lane) * 512 + f] = (_Float16)((en - (float)h1) * 2048.0f);
      } else {
        a.gbias[lane] = g;
      }
    }
  }
  grid.sync();

  // ---------------- P3: scoring GEMM, K-split 8, all 512 blocks -------------
  {
    _Float16* Bh = (_Float16*)shmF;   // 8192 halfs
    _Float16* Bl = Bh + 8192;         // 8192
    _Float16* Ah = Bl + 8192;         // 2048
    _Float16* Al = Ah + 2048;         // 2048  -> 40960 B total
    int kc = bid & 7, tt = bid >> 3;  // tt 0..63
    int b0 = tt * 32, k0 = kc * 64;

    #pragma unroll
    for (int i = 0; i < 4; ++i) {
      int cw = wave * 32 + i * 8;
      int cl = cw + (lane >> 3);
      int g = (lane & 7) ^ (cl & 7);
      size_t src = (size_t)cl * 512 + k0 + g * 8;
      GLL(a.GhT + src, Bh + cw * 64);
      GLL(a.GlT + src, Bl + cw * 64);
    }
    {
      int tw = wave * 8;
      int tkl = tw + (lane >> 3);
      int g = (lane & 7) ^ (tkl & 7);
      size_t asrc = (size_t)(b0 + tkl) * 512 + k0 + g * 8;
      GLL(a.Fh + asrc, Ah + tw * 64);
      GLL(a.Fl + asrc, Al + tw * 64);
    }
    __syncthreads();

    f32x4 accH[2][2], accM[2][2];
    #pragma unroll
    for (int mt = 0; mt < 2; ++mt)
      #pragma unroll
      for (int ct = 0; ct < 2; ++ct) {
        accH[mt][ct] = (f32x4){0.f, 0.f, 0.f, 0.f};
        accM[mt][ct] = (f32x4){0.f, 0.f, 0.f, 0.f};
      }
    int kg = lane >> 4, mrow = lane & 15;
    #pragma unroll
    for (int kh = 0; kh < 2; ++kh) {
      int gq = kh * 4 + kg;
      half8 afh[2], afl[2], bfh[2], bfl[2];
      #pragma unroll
      for (int mt = 0; mt < 2; ++mt) {
        int tr = mt * 16 + mrow;
        int off = tr * 64 + ((gq ^ (tr & 7)) * 8);
        afh[mt] = *(const half8*)(Ah + off);
        afl[mt] = *(const half8*)(Al + off);
      }
      #pragma unroll
      for (int ct = 0; ct < 2; ++ct) {
        int cl = wave * 32 + ct * 16 + mrow;
        int off = cl * 64 + ((gq ^ (cl & 7)) * 8);
        bfh[ct] = *(const half8*)(Bh + off);
        bfl[ct] = *(const half8*)(Bl + off);
      }
      #pragma unroll
      for (int mt = 0; mt < 2; ++mt)
        #pragma unroll
        for (int ct = 0; ct < 2; ++ct) {
          accH[mt][ct] = __builtin_amdgcn_mfma_f32_16x16x32_f16(
              afh[mt], bfh[ct], accH[mt][ct], 0, 0, 0);
          accM[mt][ct] = __builtin_amdgcn_mfma_f32_16x16x32_f16(
              afh[mt], bfl[ct], accM[mt][ct], 0, 0, 0);
          accM[mt][ct] = __builtin_amdgcn_mfma_f32_16x16x32_f16(
              afl[mt], bfh[ct], accM[mt][ct], 0, 0, 0);
        }
    }
    int rbase = (lane >> 4) * 4;
    #pragma unroll
    for (int mt = 0; mt < 2; ++mt)
      #pragma unroll
      for (int ct = 0; ct < 2; ++ct)
        #pragma unroll
        for (int r = 0; r < 4; ++r) {
          int tok = b0 + mt * 16 + rbase + r;
          int col = wave * 32 + ct * 16 + mrow;
          a.scores8[((size_t)(kc * 2048 + tok) << 7) + col] =
              accH[mt][ct][r] + accM[mt][ct][r] * (1.0f / 2048.0f);
        }
  }
  grid.sync();

  // ---------------- P4: rank-based top-8 (wave = one token) -----------------
  {
    float* sc = shmF + wave * 64;
    float* ex8 = shmF + 1024 + wave * 8;
    int b = bid * 4 + wave;
    float l = 0.f, s = 0.f;
    #pragma unroll
    for (int kc = 0; kc < 8; ++kc) {
      const float* row = a.scores8 + ((size_t)(kc * 2048 + b) << 7);
      l += row[lane];
      s += row[64 + lane];
    }
    float inv_n = 1.0f / fmaxf(sqrtf(a.fnorm[b]), 1e-8f);
    float gate = 1.0f / (1.0f + expf(-(l + a.gbias[lane]) * 0.0625f));
    float sim = fmaxf(s * inv_n, 0.0f);
    float score = gate * sim * a.coef[lane];
    sc[lane] = score;
    int rank = 0;
    float mx = score;
    #pragma unroll 8
    for (int j = 0; j < 64; ++j) {
      float sj = sc[j];
      rank += (sj > score || (sj == score && j < lane)) ? 1 : 0;
      mx = fmaxf(mx, sj);
    }
    float ev = expf(score - mx);
    if (rank < 8) ex8[rank] = ev;
    float sum = 0.f;
    #pragma unroll
    for (int r = 0; r < 8; ++r) sum += ex8[r];
    if (rank < 8) {
      a.sel[b * 8 + rank] = lane;
      a.selw[b * 8 + rank] = ev / sum;
    }
  }
  grid.sync();

  // ---------------- P5: per-expert gather + jobs ----------------------------
  if (bid < 64) {
    int* lcnt = (int*)shmF;
    int e = bid;
    if (tid == 0) lcnt[0] = 0;
    __syncthreads();
    for (int q = 0; q < 64; ++q) {
      int i = q * 256 + tid;
      if (a.sel[i] == e) {
        int pos = atomicAdd(lcnt, 1);
        a.tlist[e * B_N + pos] = (i >> 3) | ((i & 7) << 12);
        a.wlist[e * B_N + pos] = a.selw[i];
      }
    }
    __syncthreads();
    if (tid == 0) {
      int c = lcnt[0];
      a.cnt[e] = c;
      int nt = (c + 63) >> 6;
      int base = atomicAdd(a.njobs, nt);
      for (int t = 0; t < nt; ++t) a.jobs[base + t] = (e << 8) | t;
    }
  }
  grid.sync();

  // ---------------- P6: gathered FST GEMM (grid-stride over jobs*4) ---------
  {
    _Float16* Bh = (_Float16*)shmF;       // 2 x 8192 halfs
    _Float16* Ah = Bh + 16384;            // 2 x 4096 halfs
    int* tl = (int*)(Ah + 8192);          // 64
    float* wl = (float*)(tl + 64);        // 64  -> 49664 B total
    int kg = lane >> 4, mrow = lane & 15;
    int nj4 = a.njobs[0] * 4;
    for (int vb = bid; vb < nj4; vb += 512) {
      __syncthreads();  // prior iteration's epilogue done before tl reuse
      int job = vb >> 2, chunk = vb & 3;
      int jb = a.jobs[job];
      int e = jb >> 8, tile = jb & 255;
      int c0 = chunk * 128, c_e = a.cnt[e], t0 = tile * 64;
      if (tid < 64) {
        int t = t0 + tid;
        tl[tid] = a.tlist[e * B_N + (t < c_e ? t : t0)];
        wl[tid] = (t < c_e) ? a.wlist[e * B_N + t] : 0.0f;
      }
      __syncthreads();

      const _Float16* WhT_e = a.WhT + ((size_t)e << 18);
      size_t bsrc[4];
      int bdst[4];
      #pragma unroll
      for (int i = 0; i < 4; ++i) {
        int cw = wave * 32 + i * 8;
        int cl = cw + (lane >> 3);
        int g = (lane & 7) ^ (cl & 7);
        bsrc[i] = (size_t)(c0 + cl) * 512 + g * 8;
        bdst[i] = cw * 64;
      }
      size_t asrc[2];
      int adst[2];
      #pragma unroll
      for (int j = 0; j < 2; ++j) {
        int tw = wave * 16 + j * 8;
        int tkl = tw + (lane >> 3);
        int g = (lane & 7) ^ (tkl & 7);
        asrc[j] = (size_t)(tl[tkl] & 4095) * 512 + g * 8;
        adst[j] = tw * 64;
      }
      f32x4 acc[4][2];
      #pragma unroll
      for (int mt = 0; mt < 4; ++mt)
        #pragma unroll
        for (int ct = 0; ct < 2; ++ct) acc[mt][ct] = (f32x4){0.f, 0.f, 0.f, 0.f};

      #define STG6(K0S, BUF)                                                  \
        do {                                                                  \
          _Pragma("unroll")                                                   \
          for (int i = 0; i < 4; ++i)                                         \
            GLL(WhT_e + bsrc[i] + (K0S), Bh + (BUF)*8192 + bdst[i]);          \
          _Pragma("unroll")                                                   \
          for (int j = 0; j < 2; ++j)                                         \
            GLL(a.Fh + asrc[j] + (K0S), Ah + (BUF)*4096 + adst[j]);           \
        } while (0)

      STG6(0, 0);
      __syncthreads();
      int buf = 0;
      for (int s = 0; s < 8; ++s) {
        if (s < 7) STG6((s + 1) * 64, buf ^ 1);
        #pragma unroll
        for (int kh = 0; kh < 2; ++kh) {
          int gq = kh * 4 + kg;
          half8 af[4], bf[2];
          #pragma unroll
          for (int mt = 0; mt < 4; ++mt) {
            int tr = mt * 16 + mrow;
            af[mt] = *(const half8*)(Ah + buf * 4096 + tr * 64 +
                                     ((gq ^ (tr & 7)) * 8));
          }
          #pragma unroll
          for (int ct = 0; ct < 2; ++ct) {
            int cl = wave * 32 + ct * 16 + mrow;
            bf[ct] = *(const half8*)(Bh + buf * 8192 + cl * 64 +
                                     ((gq ^ (cl & 7)) * 8));
          }
          #pragma unroll
          for (int mt = 0; mt < 4; ++mt)
            #pragma unroll
            for (int ct = 0; ct < 2; ++ct)
              acc[mt][ct] = __builtin_amdgcn_mfma_f32_16x16x32_f16(
                  af[mt], bf[ct], acc[mt][ct], 0, 0, 0);
        }
        __syncthreads();
        buf ^= 1;
      }
      #undef STG6

      int rbase = (lane >> 4) * 4;
      int colbase = c0 + wave * 32 + mrow;
      float bia0 = a.fst_b[e * 512 + colbase];
      float bia1 = a.fst_b[e * 512 + colbase + 16];
      #pragma unroll
      for (int mt = 0; mt < 4; ++mt) {
        #pragma unroll
        for (int r = 0; r < 4; ++r) {
          int tloc = mt * 16 + rbase + r;
          float w = wl[tloc];
          if (w != 0.0f) {
            int v = tl[tloc];
            int tok = v & 4095;
            int slot = v >> 12;
            float* yp = a.ypart + (((size_t)tok * 8 + slot) << 9) + colbase;
            yp[0] = w * (acc[mt][0][r] + bia0);
            yp[16] = w * (acc[mt][1][r] + bia1);
          }
        }
      }
    }
  }
  grid.sync();

  // ---------------- P7: reduce ypart -> out ---------------------------------
  for (int vb = bid; vb < 2048; vb += 512) {
    #pragma unroll
    for (int q = 0; q < 2; ++q) {
      int f = tid + q * 256;
      float acc = 0.0f;
      #pragma unroll
      for (int s = 0; s < 8; ++s)
        acc += a.ypart[(((size_t)vb * 8 + s) << 9) + f];
      a.out[(size_t)vb * 512 + f] = acc;
    }
  }
}

// ================= FALLBACK: r11 7-kernel path ==============================
__global__ __launch_bounds__(256) void k_prep(
    const float* __restrict__ proj_w, const float* __restrict__ expert_emb,
    const float* __restrict__ expert_features, const float* __restrict__ trust,
    const float* __restrict__ dt, const float* __restrict__ features,
    const float* __restrict__ fst_w, float* __restrict__ pwT,
    float* __restrict__ embT, float* __restrict__ enT,
    float* __restrict__ coef, int* __restrict__ cnt, _Float16* __restrict__ Fh,
    _Float16* __restrict__ Fl, float* __restrict__ fnorm,
    _Float16* __restrict__ WhT, int* __restrict__ njobs) {
  __shared__ float tile[16704];
  __shared__ float parts[4];
  int bid = blockIdx.x, tid = threadIdx.x;
  if (bid < 512) {
    int idx = bid * 256 + tid;
    int f = idx >> 8, h = idx & 255;
    pwT[idx] = proj_w[h * 512 + f];
    if (bid == 0 && tid < E_N) cnt[tid] = 0;
    if (bid == 0 && tid == 64) njobs[0] = 0;
  } else if (bid < 576) {
    int e = bid - 512;
    float v0 = expert_features[e * 512 + tid];
    float v1 = expert_features[e * 512 + tid + 256];
    float ss = v0 * v0 + v1 * v1;
    #pragma unroll
    for (int off = 32; off; off >>= 1) ss += __shfl_xor(ss, off);
    if ((tid & 63) == 0) parts[tid >> 6] = ss;
    __syncthreads();
    float tot = parts[0] + parts[1] + parts[2] + parts[3];
    float inv = 1.0f / fmaxf(sqrtf(tot), 1e-8f);
    enT[tid * 64 + e] = v0 * inv;
    enT[(tid + 256) * 64 + e] = v1 * inv;
    embT[tid * 64 + e] = expert_emb[e * 256 + tid];
    if (tid == 0) {
      float st = fmaxf(0.1f, expf(-0.005f * dt[e]));
      coef[e] = trust[e] * st;
    }
  } else if (bid < 1088) {
    int gid = (bid - 576) * 256 + tid;
    int i = gid * 8;
    float4 v0 = *(const float4*)(features + i);
    float4 v1 = *(const float4*)(features + i + 4);
    float xs[8] = {v0.x, v0.y, v0.z, v0.w, v1.x, v1.y, v1.z, v1.w};
    half8 h, l;
    float ss = 0.0f;
    #pragma unroll
    for (int j = 0; j < 8; ++j) {
      h[j] = (_Float16)xs[j];
      l[j] = (_Float16)((xs[j] - (float)h[j]) * 2048.0f);
      ss = fmaf(xs[j], xs[j], ss);
    }
    *(half8*)(Fh + i) = h;
    *(half8*)(Fl + i) = l;
    #pragma unroll
    for (int off = 32; off; off >>= 1) ss += __shfl_xor(ss, off);
    if ((tid & 63) == 0) fnorm[gid >> 6] = ss;
  } else {
    int b2 = bid - 1088;
    int e = b2 >> 4;
    int kb = (b2 >> 1) & 7;
    int cb = b2 & 1;
    const float* src = fst_w + ((size_t)e << 18) + (size_t)(kb * 64) * 512 +
                       cb * 256;
    int kr = tid >> 6;
    int c4 = (tid & 63) * 4;
    #pragma unroll
    for (int r = 0; r < 16; ++r) {
      int k = r * 4 + kr;
      *(float4*)&tile[k * 260 + ((k >> 3) << 2) + c4] =
          *(const float4*)&src[(size_t)k * 512 + c4];
    }
    __syncthreads();
    int co = tid >> 3;
    int ko = (tid & 7) * 8;
    #pragma unroll
    for (int g = 0; g < 8; ++g) {
      int c = g * 32 + co;
      half8 vh;
      #pragma unroll
      for (int i = 0; i < 8; ++i) {
        int k = ko + i;
        vh[i] = (_Float16)tile[k * 260 + ((k >> 3) << 2) + c];
      }
      size_t dbase =
          ((size_t)e << 18) + (size_t)(cb * 256 + c) * 512 + kb * 64 + ko;
      *(half8*)(WhT + dbase) = vh;
    }
  }
}

__global__ __launch_bounds__(64) void k0gs(
    const float* __restrict__ pwT, const float* __restrict__ proj_b,
    const float* __restrict__ embT, const float* __restrict__ enT,
    _Float16* __restrict__ GhT, _Float16* __restrict__ GlT,
    float* __restrict__ gbias) {
  __shared__ float row[256];
  int f = blockIdx.x;
  int e = threadIdx.x;
  const float* src = (f < 512) ? (pwT + f * 256) : proj_b;
  *(float4*)&row[e * 4] = *(const float4*)&src[e * 4];
  __syncthreads();
  float g = 0.0f;
  #pragma unroll 8
  for (int h = 0; h < 256; ++h) g = fmaf(row[h], embT[h * 64 + e], g);
  if (f < 512) {
    _Float16 h0 = (_Float16)g;
    GhT[e * 512 + f] = h0;
    GlT[e * 512 + f] = (_Float16)((g - (float)h0) * 2048.0f);
    float en = enT[f * 64 + e];
    _Float16 h1 = (_Float16)en;
    GhT[(64 + e) * 512 + f] = h1;
    GlT[(64 + e) * 512 + f] = (_Float16)((en - (float)h1) * 2048.0f);
  } else {
    gbias[e] = g;
  }
}

__global__ __launch_bounds__(256, 2) void k1a_mfma(
    const _Float16* __restrict__ Fh, const _Float16* __restrict__ Fl,
    const _Float16* __restrict__ GhT, const _Float16* __restrict__ GlT,
    float* __restrict__ scores4) {
  __shared__ _Float16 Bh[2][128 * 64];
  __shared__ _Float16 Bl[2][128 * 64];
  __shared__ _Float16 Ah[2][32 * 64];
  __shared__ _Float16 Al[2][32 * 64];
  int tid = threadIdx.x;
  int kc = blockIdx.x & 3;
  int tt = blockIdx.x >> 2;
  int b0 = tt * 32;
  int k0 = kc * 128;
  int wave = tid >> 6, lane = tid & 63;
  size_t bsrc[4];
  int bdst[4];
  #pragma unroll
  for (int i = 0; i < 4; ++i) {
    int cw = wave * 32 + i * 8;
    int cl = cw + (lane >> 3);
    int g = (lane & 7) ^ (cl & 7);
    bsrc[i] = (size_t)cl * 512 + k0 + g * 8;
    bdst[i] = cw * 64;
  }
  int tw = wave * 8;
  int tkl = tw + (lane >> 3);
  int ga = (lane & 7) ^ (tkl & 7);
  size_t asrc = (size_t)(b0 + tkl) * 512 + k0 + ga * 8;
  int adst = tw * 64;
  f32x4 accH[2][2], accM[2][2];
  #pragma unroll
  for (int mt = 0; mt < 2; ++mt)
    #pragma unroll
    for (int ct = 0; ct < 2; ++ct) {
      accH[mt][ct] = (f32x4){0.f, 0.f, 0.f, 0.f};
      accM[mt][ct] = (f32x4){0.f, 0.f, 0.f, 0.f};
    }
  int kg = lane >> 4;
  int mrow = lane & 15;
  #define STG(K0S, BUF)                                                       \
    do {                                                                      \
      _Pragma("unroll")                                                       \
      for (int i = 0; i < 4; ++i) {                                           \
        GLL(GhT + bsrc[i] + (K0S), &Bh[BUF][0] + bdst[i]);                    \
        GLL(GlT + bsrc[i] + (K0S), &Bl[BUF][0] + bdst[i]);                    \
      }                                                                       \
      GLL(Fh + asrc + (K0S), &Ah[BUF][0] + adst);                             \
      GLL(Fl + asrc + (K0S), &Al[BUF][0] + adst);                             \
    } while (0)
  STG(0, 0);
  __syncthreads();
  int buf = 0;
  #pragma unroll
  for (int s = 0; s < 2; ++s) {
    if (s < 1) STG(64, 1);
    #pragma unroll
    for (int kh = 0; kh < 2; ++kh) {
      int gq = kh * 4 + kg;
      half8 afh[2], afl[2], bfh[2], bfl[2];
      #pragma unroll
      for (int mt = 0; mt < 2; ++mt) {
        int tr = mt * 16 + mrow;
        int off = tr * 64 + ((gq ^ (tr & 7)) * 8);
        afh[mt] = *(const half8*)(&Ah[buf][0] + off);
        afl[mt] = *(const half8*)(&Al[buf][0] + off);
      }
      #pragma unroll
      for (int ct = 0; ct < 2; ++ct) {
        int cl = wave * 32 + ct * 16 + mrow;
        int off = cl * 64 + ((gq ^ (cl & 7)) * 8);
        bfh[ct] = *(const half8*)(&Bh[buf][0] + off);
        bfl[ct] = *(const half8*)(&Bl[buf][0] + off);
      }
      #pragma unroll
      for (int mt = 0; mt < 2; ++mt)
        #pragma unroll
        for (int ct = 0; ct < 2; ++ct) {
          accH[mt][ct] = __builtin_amdgcn_mfma_f32_16x16x32_f16(
              afh[mt], bfh[ct], accH[mt][ct], 0, 0, 0);
          accM[mt][ct] = __builtin_amdgcn_mfma_f32_16x16x32_f16(
              afh[mt], bfl[ct], accM[mt][ct], 0, 0, 0);
          accM[mt][ct] = __builtin_amdgcn_mfma_f32_16x16x32_f16(
              afl[mt], bfh[ct], accM[mt][ct], 0, 0, 0);
        }
    }
    __syncthreads();
    buf ^= 1;
  }
  #undef STG
  int rbase = (lane >> 4) * 4;
  #pragma unroll
  for (int mt = 0; mt < 2; ++mt)
    #pragma unroll
    for (int ct = 0; ct < 2; ++ct)
      #pragma unroll
      for (int r = 0; r < 4; ++r) {
        int tok = b0 + mt * 16 + rbase + r;
        int col = wave * 32 + ct * 16 + mrow;
        scores4[((size_t)(kc * 2048 + tok) << 7) + col] =
            accH[mt][ct][r] + accM[mt][ct][r] * (1.0f / 2048.0f);
      }
}

__global__ __launch_bounds__(256) void k1b_rank(
    const float* __restrict__ scores4, const float* __restrict__ fnorm,
    const float* __restrict__ coef, const float* __restrict__ gbias,
    int* __restrict__ sel, float* __restrict__ selw) {
  __shared__ float sc[4][64];
  __shared__ float ex8[4][8];
  int tid = threadIdx.x;
  int wave = tid >> 6, lane = tid & 63;
  int b = blockIdx.x * 4 + wave;
  float l = 0.f, s = 0.f;
  #pragma unroll
  for (int kc = 0; kc < 4; ++kc) {
    const float* row = scores4 + ((size_t)(kc * 2048 + b) << 7);
    l += row[lane];
    s += row[64 + lane];
  }
  float inv_n = 1.0f / fmaxf(sqrtf(fnorm[b]), 1e-8f);
  float gate = 1.0f / (1.0f + expf(-(l + gbias[lane]) * 0.0625f));
  float sim = fmaxf(s * inv_n, 0.0f);
  float score = gate * sim * coef[lane];
  sc[wave][lane] = score;
  int rank = 0;
  float mx = score;
  #pragma unroll 8
  for (int j = 0; j < 64; ++j) {
    float sj = sc[wave][j];
    rank += (sj > score || (sj == score && j < lane)) ? 1 : 0;
    mx = fmaxf(mx, sj);
  }
  float ev = expf(score - mx);
  if (rank < 8) ex8[wave][rank] = ev;
  float sum = 0.f;
  #pragma unroll
  for (int r = 0; r < 8; ++r) sum += ex8[wave][r];
  if (rank < 8) {
    sel[b * 8 + rank] = lane;
    selw[b * 8 + rank] = ev / sum;
  }
}

__global__ __launch_bounds__(256) void k_gather(
    const int* __restrict__ sel, const float* __restrict__ selw,
    int* __restrict__ cnt, int* __restrict__ tlist, float* __restrict__ wlist,
    int* __restrict__ jobs, int* __restrict__ njobs) {
  __shared__ int lcnt;
  int e = blockIdx.x;
  int tid = threadIdx.x;
  if (tid == 0) lcnt = 0;
  __syncthreads();
  for (int q = 0; q < 64; ++q) {
    int i = q * 256 + tid;
    if (sel[i] == e) {
      int pos = atomicAdd(&lcnt, 1);
      tlist[e * B_N + pos] = (i >> 3) | ((i & 7) << 12);
      wlist[e * B_N + pos] = selw[i];
    }
  }
  __syncthreads();
  if (tid == 0) {
    int c = lcnt;
    cnt[e] = c;
    int nt = (c + 63) >> 6;
    int base = atomicAdd(njobs, nt);
    for (int t = 0; t < nt; ++t) jobs[base + t] = (e << 8) | t;
  }
}

__global__ __launch_bounds__(256, 3) void k3_mfma(
    const _Float16* __restrict__ Fh, const _Float16* __restrict__ WhT,
    const float* __restrict__ fst_b, const int* __restrict__ cnt,
    const int* __restrict__ tlist, const float* __restrict__ wlist,
    const int* __restrict__ jobs, const int* __restrict__ njobs,
    float* __restrict__ ypart) {
  __shared__ _Float16 Bh[2][128 * 64];
  __shared__ _Float16 Ah[2][64 * 64];
  __shared__ int tl[64];
  __shared__ float wl[64];
  int tid = threadIdx.x;
  int job = blockIdx.x >> 2;
  int chunk = blockIdx.x & 3;
  if (job >= njobs[0]) return;
  int jb = jobs[job];
  int e = jb >> 8;
  int tile = jb & 255;
  int c0 = chunk * 128;
  int c_e = cnt[e];
  int t0 = tile * 64;
  if (tid < 64) {
    int t = t0 + tid;
    tl[tid] = tlist[e * B_N + (t < c_e ? t : t0)];
    wl[tid] = (t < c_e) ? wlist[e * B_N + t] : 0.0f;
  }
  __syncthreads();
  int wave = tid >> 6, lane = tid & 63;
  const _Float16* WhT_e = WhT + ((size_t)e << 18);
  size_t bsrc[4];
  int bdst[4];
  #pragma unroll
  for (int i = 0; i < 4; ++i) {
    int cw = wave * 32 + i * 8;
    int cl = cw + (lane >> 3);
    int g = (lane & 7) ^ (cl & 7);
    bsrc[i] = (size_t)(c0 + cl) * 512 + g * 8;
    bdst[i] = cw * 64;
  }
  size_t asrc[2];
  int adst[2];
  #pragma unroll
  for (int j = 0; j < 2; ++j) {
    int tw = wave * 16 + j * 8;
    int tkl = tw + (lane >> 3);
    int g = (lane & 7) ^ (tkl & 7);
    asrc[j] = (size_t)(tl[tkl] & 4095) * 512 + g * 8;
    adst[j] = tw * 64;
  }
  f32x4 acc[4][2];
  #pragma unroll
  for (int mt = 0; mt < 4; ++mt)
    #pragma unroll
    for (int ct = 0; ct < 2; ++ct) acc[mt][ct] = (f32x4){0.f, 0.f, 0.f, 0.f};
  int kg = lane >> 4;
  int mrow = lane & 15;
  #define STAGE(K0S, BUF)                                                     \
    do {                                                                      \
      _Pragma("unroll")                                                       \
      for (int i = 0; i < 4; ++i)                                             \
        GLL(WhT_e + bsrc[i] + (K0S), &Bh[BUF][0] + bdst[i]);                  \
      _Pragma("unroll")                                                       \
      for (int j = 0; j < 2; ++j)                                             \
        GLL(Fh + asrc[j] + (K0S), &Ah[BUF][0] + adst[j]);                     \
    } while (0)
  STAGE(0, 0);
  __syncthreads();
  int buf = 0;
  for (int s = 0; s < 8; ++s) {
    if (s < 7) STAGE((s + 1) * 64, buf ^ 1);
    #pragma unroll
    for (int kh = 0; kh < 2; ++kh) {
      int gq = kh * 4 + kg;
      half8 af[4], bf[2];
      #pragma unroll
      for (int mt = 0; mt < 4; ++mt) {
        int tr = mt * 16 + mrow;
        af[mt] = *(const half8*)(&Ah[buf][0] + tr * 64 + ((gq ^ (tr & 7)) * 8));
      }
      #pragma unroll
      for (int ct = 0; ct < 2; ++ct) {
        int cl = wave * 32 + ct * 16 + mrow;
        bf[ct] = *(const half8*)(&Bh[buf][0] + cl * 64 + ((gq ^ (cl & 7)) * 8));
      }
      #pragma unroll
      for (int mt = 0; mt < 4; ++mt)
        #pragma unroll
        for (int ct = 0; ct < 2; ++ct)
          acc[mt][ct] = __builtin_amdgcn_mfma_f32_16x16x32_f16(
              af[mt], bf[ct], acc[mt][ct], 0, 0, 0);
    }
    __syncthreads();
    buf ^= 1;
  }
  #undef STAGE
  int rbase = (lane >> 4) * 4;
  int colbase = c0 + wave * 32 + mrow;
  float bia0 = fst_b[e * 512 + colbase];
  float bia1 = fst_b[e * 512 + colbase + 16];
  #pragma unroll
  for (int mt = 0; mt < 4; ++mt) {
    #pragma unroll
    for (int r = 0; r < 4; ++r) {
      int tloc = mt * 16 + rbase + r;
      float w = wl[tloc];
      if (w != 0.0f) {
        int v = tl[tloc];
        int tok = v & 4095;
        int slot = v >> 12;
        float* yp = ypart + (((size_t)tok * 8 + slot) << 9) + colbase;
        yp[0] = w * (acc[mt][0][r] + bia0);
        yp[16] = w * (acc[mt][1][r] + bia1);
      }
    }
  }
}

__global__ __launch_bounds__(256) void k4_reduce(const float* __restrict__ ypart,
                                                 float* __restrict__ out) {
  int b = blockIdx.x, tid = threadIdx.x;
  #pragma unroll
  for (int q = 0; q < 2; ++q) {
    int f = tid + q * 256;
    float a = 0.0f;
    #pragma unroll
    for (int s = 0; s < 8; ++s) a += ypart[(((size_t)b * 8 + s) << 9) + f];
    out[(size_t)b * 512 + f] = a;
  }
}

// ================= FP32 minimal fallback (tiny ws) ==========================
__global__ __launch_bounds__(64) void k0g(
    const float* __restrict__ pwT, const float* __restrict__ proj_b,
    const float* __restrict__ embT, const float* __restrict__ enT,
    float* __restrict__ Gpack, float* __restrict__ gbias) {
  __shared__ float row[256];
  int f = blockIdx.x;
  int e = threadIdx.x;
  const float* src = (f < 512) ? (pwT + f * 256) : proj_b;
  *(float4*)&row[e * 4] = *(const float4*)&src[e * 4];
  __syncthreads();
  float g = 0.0f;
  #pragma unroll 8
  for (int h = 0; h < 256; ++h) g = fmaf(row[h], embT[h * 64 + e], g);
  if (f < 512) {
    Gpack[(f * 64 + e) * 2 + 0] = g;
    Gpack[(f * 64 + e) * 2 + 1] = enT[f * 64 + e];
  } else {
    gbias[e] = g;
  }
}

__global__ __launch_bounds__(256) void k1_score(
    const float* __restrict__ features, const float* __restrict__ Gpack,
    const float* __restrict__ gbias, const float* __restrict__ coef,
    int* __restrict__ cnt, int* __restrict__ tk_idx, float* __restrict__ tk_w,
    int* __restrict__ tlist, float* __restrict__ wlist) {
  __shared__ float Ft[2][512];
  __shared__ float pl[4][64];
  __shared__ float ps[4][64];
  __shared__ float pn[4];
  int tid = threadIdx.x;
  int b0 = blockIdx.x * 2;
  {
    int t = tid >> 7;
    int fo = (tid & 127) * 4;
    *(float4*)&Ft[t][fo] =
        *(const float4*)&features[(size_t)(b0 + t) * 512 + fo];
  }
  __syncthreads();
  int wave = tid >> 6, e = tid & 63;
  int tok = wave & 1;
  int f0 = (wave >> 1) * 256;
  float la = 0.f, lb = 0.f, sa = 0.f, sb = 0.f;
  #pragma unroll 4
  for (int f = f0; f < f0 + 256; f += 2) {
    float2 g0 = *(const float2*)&Gpack[(f * 64 + e) * 2];
    float2 g1 = *(const float2*)&Gpack[((f + 1) * 64 + e) * 2];
    float x0 = Ft[tok][f];
    float x1 = Ft[tok][f + 1];
    la = fmaf(x0, g0.x, la);
    sa = fmaf(x0, g0.y, sa);
    lb = fmaf(x1, g1.x, lb);
    sb = fmaf(x1, g1.y, sb);
  }
  float nn = 0.f;
  #pragma unroll
  for (int j = 0; j < 4; ++j) {
    float v = Ft[tok][f0 + e + 64 * j];
    nn = fmaf(v, v, nn);
  }
  #pragma unroll
  for (int off = 32; off; off >>= 1) nn += __shfl_xor(nn, off);
  pl[wave][e] = la + lb;
  ps[wave][e] = sa + sb;
  if (e == 0) pn[wave] = nn;
  __syncthreads();
  if (wave < 2) {
    int b = b0 + wave;
    float l = pl[wave][e] + pl[wave + 2][e];
    float s = ps[wave][e] + ps[wave + 2][e];
    float ntot = pn[wave] + pn[wave + 2];
    float inv_n = 1.0f / fmaxf(sqrtf(ntot), 1e-8f);
    float gate = 1.0f / (1.0f + expf(-(l + gbias[e]) * 0.0625f));
    float sim = fmaxf(s * inv_n, 0.0f);
    float score = gate * sim * coef[e];
    float cur = score;
    float bv[8];
    int bi[8];
    #pragma unroll
    for (int r = 0; r < 8; ++r) {
      float mv = cur;
      int mi = e;
      #pragma unroll
      for (int off = 1; off < 64; off <<= 1) {
        float ov = __shfl_xor(mv, off);
        int oi = __shfl_xor(mi, off);
        if (ov > mv || (ov == mv && oi < mi)) { mv = ov; mi = oi; }
      }
      bv[r] = mv;
      bi[r] = mi;
      if (e == mi) cur = -1.0f;
    }
    float m0 = bv[0];
    float ex[8];
    float sum = 0.0f;
    #pragma unroll
    for (int r = 0; r < 8; ++r) { ex[r] = expf(bv[r] - m0); sum += ex[r]; }
    float isum = 1.0f / sum;
    if (e < 8) {
      int ir = 0; float er = 0.0f;
      switch (e) {
        case 0: ir = bi[0]; er = ex[0]; break;
        case 1: ir = bi[1]; er = ex[1]; break;
        case 2: ir = bi[2]; er = ex[2]; break;
        case 3: ir = bi[3]; er = ex[3]; break;
        case 4: ir = bi[4]; er = ex[4]; break;
        case 5: ir = bi[5]; er = ex[5]; break;
        case 6: ir = bi[6]; er = ex[6]; break;
        case 7: ir = bi[7]; er = ex[7]; break;
      }
      float wr = er * isum;
      int pos = atomicAdd(&cnt[ir], 1);
      tlist[ir * B_N + pos] = b;
      wlist[ir * B_N + pos] = wr;
      tk_idx[b * 8 + e] = ir;
      tk_w[b * 8 + e] = wr;
    }
  }
}

__global__ __launch_bounds__(256) void k2_bias(
    const int* __restrict__ tk_idx, const float* __restrict__ tk_w,
    const float* __restrict__ fst_b, float* __restrict__ out) {
  int b = blockIdx.x, tid = threadIdx.x;
  int ir[8];
  float wr[8];
  #pragma unroll
  for (int r = 0; r < 8; ++r) {
    ir[r] = tk_idx[b * 8 + r];
    wr[r] = tk_w[b * 8 + r];
  }
  #pragma unroll
  for (int q = 0; q < 2; ++q) {
    int f = tid + q * 256;
    float a = 0.0f;
    #pragma unroll
    for (int r = 0; r < 8; ++r) a = fmaf(wr[r], fst_b[ir[r] * 512 + f], a);
    out[(size_t)b * 512 + f] = a;
  }
}

#define TM 64
#define TN 256
#define KC 16
__global__ __launch_bounds__(256, 2) void k3_fst(
    const float* __restrict__ features, const float* __restrict__ fst_w,
    const int* __restrict__ cnt, const int* __restrict__ tlist,
    const float* __restrict__ wlist, float* __restrict__ out) {
  __shared__ float Ws[2][KC][TN];
  __shared__ float Ft[2][KC][TM];
  __shared__ int tl[TM];
  __shared__ float wl[TM];
  int tid = threadIdx.x;
  int e = blockIdx.x & 63;
  int rest = blockIdx.x >> 6;
  int tile = rest >> 1;
  int ch = rest & 1;
  int c0 = ch * TN;
  int c_e = cnt[e];
  int t0 = tile * TM;
  if (t0 >= c_e) return;
  if (tid < TM) {
    int t = t0 + tid;
    if (t < c_e) {
      tl[tid] = tlist[e * B_N + t] & 4095;
      wl[tid] = wlist[e * B_N + t];
    } else {
      tl[tid] = tlist[e * B_N + t0] & 4095;
      wl[tid] = 0.0f;
    }
  }
  __syncthreads();
  const float* fw_e = fst_w + (size_t)e * (512 * 512);
  int wave = tid >> 6, lane = tid & 63;
  int tg = wave * 2 + (lane >> 5);
  int cg = lane & 31;
  int ft_t = tid >> 2;
  int ft_fq = tid & 3;
  const float* ft_src_row = features + (size_t)tl[ft_t] * 512;
  auto stageWs = [&](int kc, int buf) {
    int f0 = kc * KC;
    #pragma unroll
    for (int r = 0; r < 4; ++r) {
      int f = wave * 4 + r;
      const float* src = fw_e + (size_t)(f0 + f) * 512 + c0 + lane * 4;
      GLL(src, &Ws[buf][f][0]);
    }
  };
  auto loadFt = [&](int kc) -> float4 {
    return *(const float4*)&ft_src_row[kc * KC + ft_fq * 4];
  };
  auto writeFt = [&](float4 v, int buf) {
    Ft[buf][ft_fq * 4 + 0][ft_t] = v.x;
    Ft[buf][ft_fq * 4 + 1][ft_t] = v.y;
    Ft[buf][ft_fq * 4 + 2][ft_t] = v.z;
    Ft[buf][ft_fq * 4 + 3][ft_t] = v.w;
  };
  float acc[8][8];
  #pragma unroll
  for (int j = 0; j < 8; ++j)
    #pragma unroll
    for (int i = 0; i < 8; ++i) acc[j][i] = 0.0f;
  auto compute = [&](int buf) {
    #pragma unroll 4
    for (int f = 0; f < KC; ++f) {
      float4 a0 = *(const float4*)&Ft[buf][f][tg * 8];
      float4 a1 = *(const float4*)&Ft[buf][f][tg * 8 + 4];
      float4 w0 = *(const float4*)&Ws[buf][f][cg * 4];
      float4 w1 = *(const float4*)&Ws[buf][f][cg * 4 + 128];
      float av[8] = {a0.x, a0.y, a0.z, a0.w, a1.x, a1.y, a1.z, a1.w};
      float wv[8] = {w0.x, w0.y, w0.z, w0.w, w1.x, w1.y, w1.z, w1.w};
      #pragma unroll
      for (int j = 0; j < 8; ++j)
        #pragma unroll
        for (int i = 0; i < 8; ++i)
          acc[j][i] = fmaf(av[j], wv[i], acc[j][i]);
    }
  };
  stageWs(0, 0);
  float4 rf = loadFt(0);
  writeFt(rf, 0);
  __syncthreads();
  for (int kc = 0; kc < 32; ++kc) {
    int cb = kc & 1, nb = cb ^ 1;
    float4 rn = make_float4(0.f, 0.f, 0.f, 0.f);
    if (kc < 31) {
      stageWs(kc + 1, nb);
      rn = loadFt(kc + 1);
    }
    compute(cb);
    if (kc < 31) writeFt(rn, nb);
    __syncthreads();
  }
  #pragma unroll
  for (int j = 0; j < 8; ++j) {
    int lt = tg * 8 + j;
    float w = wl[lt];
    if (w != 0.0f) {
      size_t orow = (size_t)tl[lt] * 512 + c0 + cg * 4;
      #pragma unroll
      for (int i = 0; i < 4; ++i) atomicAdd(&out[orow + i], w * acc[j][i]);
      #pragma unroll
      for (int i = 0; i < 4; ++i)
        atomicAdd(&out[orow + 128 + i], w * acc[j][i + 4]);
    }
  }
}

// ---------------- launch ----------------------------------------------------
extern "C" void kernel_launch(void* const* d_in, const int* in_sizes, int n_in,
                              void* d_out, int out_size, void* d_ws,
                              size_t ws_size, hipStream_t stream) {
  const float* features = (const float*)d_in[0];
  const float* proj_w = (const float*)d_in[1];
  const float* proj_b = (const float*)d_in[2];
  const float* expert_emb = (const float*)d_in[3];
  const float* expert_features = (const float*)d_in[4];
  const float* trust = (const float*)d_in[5];
  const float* dt = (const float*)d_in[6];
  const float* fst_w = (const float*)d_in[7];
  const float* fst_b = (const float*)d_in[8];
  float* out = (float*)d_out;
  float* ws = (float*)d_ws;

  float* coef = ws;                          // 64
  int* cnt = (int*)(ws + 64);                // 64
  float* gbias = ws + 128;                   // 64
  int* njobs = (int*)(ws + 192);             // 64
  int* jobs = (int*)(ws + 256);              // 2048
  int* tlist = (int*)(ws + 2304);            // 64*2048
  float* wlist = ws + 133376;                // 64*2048
  _Float16* Fh = (_Float16*)(ws + 264448);   // 2048*512 halfs
  _Float16* WhT = (_Float16*)(ws + 788736);  // 64*512*512 halfs
  float* U = ws + 9177344;                   // union region
  float* pwT = U;                            // 512*256
  float* embT = U + 131072;                  // 256*64
  float* enT = U + 147456;                   // 512*64
  _Float16* Fl = (_Float16*)(U + 180224);    // 2048*512 halfs
  _Float16* GhT = (_Float16*)(U + 704512);   // 128*512 halfs
  _Float16* GlT = (_Float16*)(U + 737280);   // 128*512 halfs
  float* fnorm = U + 770048;                 // 2048
  float* scores8 = U + 772096;               // 8*2048*128 (fallback uses 4)
  int* sel = (int*)(U + 2869248);            // 2048*8
  float* selw = U + 2885632;                 // 2048*8
  float* ypart = U;                          // 2048*8*512 (clobbers U post-sel)
  size_t need3 = (size_t)(9177344 + 8388608) * 4;

  if (ws_size >= need3) {
    MegaArgs ma;
    ma.features = features; ma.proj_w = proj_w; ma.proj_b = proj_b;
    ma.expert_emb = expert_emb; ma.expert_features = expert_features;
    ma.trust = trust; ma.dt = dt; ma.fst_w = fst_w; ma.fst_b = fst_b;
    ma.out = out;
    ma.pwT = pwT; ma.embT = embT; ma.enT = enT; ma.coef = coef;
    ma.gbias = gbias; ma.fnorm = fnorm; ma.scores8 = scores8;
    ma.selw = selw; ma.wlist = wlist; ma.ypart = ypart;
    ma.cnt = cnt; ma.njobs = njobs; ma.jobs = jobs; ma.tlist = tlist;
    ma.sel = sel;
    ma.Fh = Fh; ma.Fl = Fl; ma.GhT = GhT; ma.GlT = GlT; ma.WhT = WhT;
    void* params[] = {&ma};
    hipError_t err = hipLaunchCooperativeKernel(
        (const void*)k_mega, dim3(512), dim3(256), params, 0, stream);
    if (err != hipSuccess) {
      (void)hipGetLastError();  // clear sticky error, run 7-kernel fallback
      hipLaunchKernelGGL(k_prep, dim3(2112), dim3(256), 0, stream, proj_w,
                         expert_emb, expert_features, trust, dt, features,
                         fst_w, pwT, embT, enT, coef, cnt, Fh, Fl, fnorm, WhT,
                         njobs);
      hipLaunchKernelGGL(k0gs, dim3(513), dim3(64), 0, stream, pwT, proj_b,
                         embT, enT, GhT, GlT, gbias);
      hipLaunchKernelGGL(k1a_mfma, dim3(256), dim3(256), 0, stream, Fh, Fl,
                         GhT, GlT, scores8);
      hipLaunchKernelGGL(k1b_rank, dim3(512), dim3(256), 0, stream, scores8,
                         fnorm, coef, gbias, sel, selw);
      hipLaunchKernelGGL(k_gather, dim3(64), dim3(256), 0, stream, sel, selw,
                         cnt, tlist, wlist, jobs, njobs);
      hipLaunchKernelGGL(k3_mfma, dim3(2048), dim3(256), 0, stream, Fh, WhT,
                         fst_b, cnt, tlist, wlist, jobs, njobs, ypart);
      hipLaunchKernelGGL(k4_reduce, dim3(2048), dim3(256), 0, stream, ypart,
                         out);
    }
  } else {
    float* pwT2 = ws;
    float* embT2 = pwT2 + 131072;
    float* enT2 = embT2 + 16384;
    float* coef2 = enT2 + 32768;
    int* cnt2 = (int*)(coef2 + 64);
    int* tk_idx = cnt2 + 64;
    float* tk_w = (float*)(tk_idx + 16384);
    int* tlist2 = (int*)(tk_w + 16384);
    float* wlist2 = (float*)(tlist2 + 131072);
    float* Gpack = wlist2 + 131072;
    float* gbias2 = Gpack + 65536;
    hipLaunchKernelGGL(k_prep, dim3(576), dim3(256), 0, stream, proj_w,
                       expert_emb, expert_features, trust, dt, features, fst_w,
                       pwT2, embT2, enT2, coef2, cnt2, (_Float16*)Gpack,
                       (_Float16*)Gpack, Gpack, (_Float16*)Gpack,
                       (int*)(gbias2 + 64));
    hipLaunchKernelGGL(k0g, dim3(513), dim3(64), 0, stream, pwT2, proj_b,
                       embT2, enT2, Gpack, gbias2);
    hipLaunchKernelGGL(k1_score, dim3(1024), dim3(256), 0, stream, features,
                       Gpack, gbias2, coef2, cnt2, tk_idx, tk_w, tlist2,
                       wlist2);
    hipLaunchKernelGGL(k2_bias, dim3(2048), dim3(256), 0, stream, tk_idx,
                       tk_w, fst_b, out);
    hipLaunchKernelGGL(k3_fst, dim3(4096), dim3(256), 0, stream, features,
                       fst_w, cnt2, tlist2, wlist2, out);
  }
}

// Round 13
// 107.479 us; speedup vs baseline: 4.2675x; 4.2675x over previous
//
#include <hip/hip_runtime.h>
#include <hip/hip_fp16.h>
#include <math.h>

#define B_N 2048
#define F_N 512
#define H_N 256
#define E_N 64

typedef __attribute__((ext_vector_type(8))) _Float16 half8;
typedef __attribute__((ext_vector_type(4))) float f32x4;

#define GLL(srcp, dstp)                                                       \
  __builtin_amdgcn_global_load_lds(                                           \
      (const __attribute__((address_space(1))) void*)(srcp),                  \
      (__attribute__((address_space(3))) void*)(dstp), 16, 0, 0)

// ================= MAIN PATH (7 kernels) ====================================

// ---- k_prep: fused input transforms. grid 2112 (main) or 576 (fallback).
__global__ __launch_bounds__(256) void k_prep(
    const float* __restrict__ proj_w, const float* __restrict__ expert_emb,
    const float* __restrict__ expert_features, const float* __restrict__ trust,
    const float* __restrict__ dt, const float* __restrict__ features,
    const float* __restrict__ fst_w, float* __restrict__ pwT,
    float* __restrict__ embT, float* __restrict__ enT,
    float* __restrict__ coef, int* __restrict__ cnt, _Float16* __restrict__ Fh,
    _Float16* __restrict__ Fl, float* __restrict__ fnorm,
    _Float16* __restrict__ WhT, int* __restrict__ njobs) {
  __shared__ float tile[16704];
  __shared__ float parts[4];
  int bid = blockIdx.x, tid = threadIdx.x;
  if (bid < 512) {
    int idx = bid * 256 + tid;
    int f = idx >> 8, h = idx & 255;
    pwT[idx] = proj_w[h * 512 + f];
    if (bid == 0 && tid < E_N) cnt[tid] = 0;
    if (bid == 0 && tid == 64) njobs[0] = 0;
  } else if (bid < 576) {
    int e = bid - 512;  // 0..63
    float v0 = expert_features[e * 512 + tid];
    float v1 = expert_features[e * 512 + tid + 256];
    float ss = v0 * v0 + v1 * v1;
    #pragma unroll
    for (int off = 32; off; off >>= 1) ss += __shfl_xor(ss, off);
    if ((tid & 63) == 0) parts[tid >> 6] = ss;
    __syncthreads();
    float tot = parts[0] + parts[1] + parts[2] + parts[3];
    float inv = 1.0f / fmaxf(sqrtf(tot), 1e-8f);
    enT[tid * 64 + e] = v0 * inv;
    enT[(tid + 256) * 64 + e] = v1 * inv;
    embT[tid * 64 + e] = expert_emb[e * 256 + tid];
    if (tid == 0) {
      float st = fmaxf(0.1f, expf(-0.005f * dt[e]));
      coef[e] = trust[e] * st;
    }
  } else if (bid < 1088) {
    // convF: fp16 hi + scaled lo + row norms
    int gid = (bid - 576) * 256 + tid;
    int i = gid * 8;
    float4 v0 = *(const float4*)(features + i);
    float4 v1 = *(const float4*)(features + i + 4);
    float xs[8] = {v0.x, v0.y, v0.z, v0.w, v1.x, v1.y, v1.z, v1.w};
    half8 h, l;
    float ss = 0.0f;
    #pragma unroll
    for (int j = 0; j < 8; ++j) {
      h[j] = (_Float16)xs[j];
      l[j] = (_Float16)((xs[j] - (float)h[j]) * 2048.0f);
      ss = fmaf(xs[j], xs[j], ss);
    }
    *(half8*)(Fh + i) = h;
    *(half8*)(Fl + i) = l;
    #pragma unroll
    for (int off = 32; off; off >>= 1) ss += __shfl_xor(ss, off);
    if ((tid & 63) == 0) fnorm[gid >> 6] = ss;
  } else {
    // convW: fst_w -> transposed fp16 [e][col][k]
    int b2 = bid - 1088;  // 1024 = 64e x 8kb x 2cb
    int e = b2 >> 4;
    int kb = (b2 >> 1) & 7;
    int cb = b2 & 1;
    const float* src = fst_w + ((size_t)e << 18) + (size_t)(kb * 64) * 512 +
                       cb * 256;
    int kr = tid >> 6;
    int c4 = (tid & 63) * 4;
    #pragma unroll
    for (int r = 0; r < 16; ++r) {
      int k = r * 4 + kr;
      *(float4*)&tile[k * 260 + ((k >> 3) << 2) + c4] =
          *(const float4*)&src[(size_t)k * 512 + c4];
    }
    __syncthreads();
    int co = tid >> 3;
    int ko = (tid & 7) * 8;
    #pragma unroll
    for (int g = 0; g < 8; ++g) {
      int c = g * 32 + co;
      half8 vh;
      #pragma unroll
      for (int i = 0; i < 8; ++i) {
        int k = ko + i;
        vh[i] = (_Float16)tile[k * 260 + ((k >> 3) << 2) + c];
      }
      size_t dbase =
          ((size_t)e << 18) + (size_t)(cb * 256 + c) * 512 + kb * 64 + ko;
      *(half8*)(WhT + dbase) = vh;
    }
  }
}

// ---- k0gs: gate matrix + enT -> fp16 2-term GhT/GlT [128 col][512 k]; gbias
__global__ __launch_bounds__(64) void k0gs(
    const float* __restrict__ pwT, const float* __restrict__ proj_b,
    const float* __restrict__ embT, const float* __restrict__ enT,
    _Float16* __restrict__ GhT, _Float16* __restrict__ GlT,
    float* __restrict__ gbias) {
  __shared__ float row[256];
  int f = blockIdx.x;
  int e = threadIdx.x;
  const float* src = (f < 512) ? (pwT + f * 256) : proj_b;
  *(float4*)&row[e * 4] = *(const float4*)&src[e * 4];
  __syncthreads();
  float g = 0.0f;
  #pragma unroll 8
  for (int h = 0; h < 256; ++h) g = fmaf(row[h], embT[h * 64 + e], g);
  if (f < 512) {
    _Float16 h0 = (_Float16)g;
    GhT[e * 512 + f] = h0;
    GlT[e * 512 + f] = (_Float16)((g - (float)h0) * 2048.0f);
    float en = enT[f * 64 + e];
    _Float16 h1 = (_Float16)en;
    GhT[(64 + e) * 512 + f] = h1;
    GlT[(64 + e) * 512 + f] = (_Float16)((en - (float)h1) * 2048.0f);
  } else {
    gbias[e] = g;
  }
}

// ---- k1a: scoring GEMM via MFMA, fp16 2-term, K-split 4 --------------------
__global__ __launch_bounds__(256, 2) void k1a_mfma(
    const _Float16* __restrict__ Fh, const _Float16* __restrict__ Fl,
    const _Float16* __restrict__ GhT, const _Float16* __restrict__ GlT,
    float* __restrict__ scores4) {
  __shared__ _Float16 Bh[2][128 * 64];
  __shared__ _Float16 Bl[2][128 * 64];
  __shared__ _Float16 Ah[2][32 * 64];
  __shared__ _Float16 Al[2][32 * 64];
  int tid = threadIdx.x;
  int kc = blockIdx.x & 3;
  int tt = blockIdx.x >> 2;
  int b0 = tt * 32;
  int k0 = kc * 128;
  int wave = tid >> 6, lane = tid & 63;
  size_t bsrc[4];
  int bdst[4];
  #pragma unroll
  for (int i = 0; i < 4; ++i) {
    int cw = wave * 32 + i * 8;
    int cl = cw + (lane >> 3);
    int g = (lane & 7) ^ (cl & 7);
    bsrc[i] = (size_t)cl * 512 + k0 + g * 8;
    bdst[i] = cw * 64;
  }
  int tw = wave * 8;
  int tkl = tw + (lane >> 3);
  int ga = (lane & 7) ^ (tkl & 7);
  size_t asrc = (size_t)(b0 + tkl) * 512 + k0 + ga * 8;
  int adst = tw * 64;
  f32x4 accH[2][2], accM[2][2];
  #pragma unroll
  for (int mt = 0; mt < 2; ++mt)
    #pragma unroll
    for (int ct = 0; ct < 2; ++ct) {
      accH[mt][ct] = (f32x4){0.f, 0.f, 0.f, 0.f};
      accM[mt][ct] = (f32x4){0.f, 0.f, 0.f, 0.f};
    }
  int kg = lane >> 4;
  int mrow = lane & 15;
  #define STG(K0S, BUF)                                                       \
    do {                                                                      \
      _Pragma("unroll")                                                       \
      for (int i = 0; i < 4; ++i) {                                           \
        GLL(GhT + bsrc[i] + (K0S), &Bh[BUF][0] + bdst[i]);                    \
        GLL(GlT + bsrc[i] + (K0S), &Bl[BUF][0] + bdst[i]);                    \
      }                                                                       \
      GLL(Fh + asrc + (K0S), &Ah[BUF][0] + adst);                             \
      GLL(Fl + asrc + (K0S), &Al[BUF][0] + adst);                             \
    } while (0)
  STG(0, 0);
  __syncthreads();
  int buf = 0;
  #pragma unroll
  for (int s = 0; s < 2; ++s) {
    if (s < 1) STG(64, 1);
    #pragma unroll
    for (int kh = 0; kh < 2; ++kh) {
      int gq = kh * 4 + kg;
      half8 afh[2], afl[2], bfh[2], bfl[2];
      #pragma unroll
      for (int mt = 0; mt < 2; ++mt) {
        int tr = mt * 16 + mrow;
        int off = tr * 64 + ((gq ^ (tr & 7)) * 8);
        afh[mt] = *(const half8*)(&Ah[buf][0] + off);
        afl[mt] = *(const half8*)(&Al[buf][0] + off);
      }
      #pragma unroll
      for (int ct = 0; ct < 2; ++ct) {
        int cl = wave * 32 + ct * 16 + mrow;
        int off = cl * 64 + ((gq ^ (cl & 7)) * 8);
        bfh[ct] = *(const half8*)(&Bh[buf][0] + off);
        bfl[ct] = *(const half8*)(&Bl[buf][0] + off);
      }
      #pragma unroll
      for (int mt = 0; mt < 2; ++mt)
        #pragma unroll
        for (int ct = 0; ct < 2; ++ct) {
          accH[mt][ct] = __builtin_amdgcn_mfma_f32_16x16x32_f16(
              afh[mt], bfh[ct], accH[mt][ct], 0, 0, 0);
          accM[mt][ct] = __builtin_amdgcn_mfma_f32_16x16x32_f16(
              afh[mt], bfl[ct], accM[mt][ct], 0, 0, 0);
          accM[mt][ct] = __builtin_amdgcn_mfma_f32_16x16x32_f16(
              afl[mt], bfh[ct], accM[mt][ct], 0, 0, 0);
        }
    }
    __syncthreads();
    buf ^= 1;
  }
  #undef STG
  int rbase = (lane >> 4) * 4;
  #pragma unroll
  for (int mt = 0; mt < 2; ++mt)
    #pragma unroll
    for (int ct = 0; ct < 2; ++ct)
      #pragma unroll
      for (int r = 0; r < 4; ++r) {
        int tok = b0 + mt * 16 + rbase + r;
        int col = wave * 32 + ct * 16 + mrow;
        scores4[((size_t)(kc * 2048 + tok) << 7) + col] =
            accH[mt][ct][r] + accM[mt][ct][r] * (1.0f / 2048.0f);
      }
}

// ---- k1b: rank-based top-8 (no butterfly, no global atomics) ---------------
__global__ __launch_bounds__(256) void k1b_rank(
    const float* __restrict__ scores4, const float* __restrict__ fnorm,
    const float* __restrict__ coef, const float* __restrict__ gbias,
    int* __restrict__ sel, float* __restrict__ selw) {
  __shared__ float sc[4][64];
  __shared__ float ex8[4][8];
  int tid = threadIdx.x;
  int wave = tid >> 6, lane = tid & 63;
  int b = blockIdx.x * 4 + wave;
  float l = 0.f, s = 0.f;
  #pragma unroll
  for (int kc = 0; kc < 4; ++kc) {
    const float* row = scores4 + ((size_t)(kc * 2048 + b) << 7);
    l += row[lane];
    s += row[64 + lane];
  }
  float inv_n = 1.0f / fmaxf(sqrtf(fnorm[b]), 1e-8f);
  float gate = 1.0f / (1.0f + expf(-(l + gbias[lane]) * 0.0625f));
  float sim = fmaxf(s * inv_n, 0.0f);
  float score = gate * sim * coef[lane];
  sc[wave][lane] = score;
  int rank = 0;
  float mx = score;
  #pragma unroll 8
  for (int j = 0; j < 64; ++j) {
    float sj = sc[wave][j];
    rank += (sj > score || (sj == score && j < lane)) ? 1 : 0;
    mx = fmaxf(mx, sj);
  }
  float ev = expf(score - mx);
  if (rank < 8) ex8[wave][rank] = ev;
  float sum = 0.f;
  #pragma unroll
  for (int r = 0; r < 8; ++r) sum += ex8[wave][r];
  if (rank < 8) {
    sel[b * 8 + rank] = lane;
    selw[b * 8 + rank] = ev / sum;
  }
}

// ---- k_gather: per-expert compaction; emits 128-token tiles ----------------
__global__ __launch_bounds__(256) void k_gather(
    const int* __restrict__ sel, const float* __restrict__ selw,
    int* __restrict__ cnt, int* __restrict__ tlist, float* __restrict__ wlist,
    int* __restrict__ jobs, int* __restrict__ njobs) {
  __shared__ int lcnt;
  int e = blockIdx.x;
  int tid = threadIdx.x;
  if (tid == 0) lcnt = 0;
  __syncthreads();
  for (int q = 0; q < 64; ++q) {
    int i = q * 256 + tid;
    if (sel[i] == e) {
      int pos = atomicAdd(&lcnt, 1);
      tlist[e * B_N + pos] = (i >> 3) | ((i & 7) << 12);  // token | slot<<12
      wlist[e * B_N + pos] = selw[i];
    }
  }
  __syncthreads();
  if (tid == 0) {
    int c = lcnt;
    cnt[e] = c;
    int nt = (c + 127) >> 7;  // 128-token tiles
    int base = atomicAdd(njobs, nt);
    for (int t = 0; t < nt; ++t) jobs[base + t] = (e << 8) | t;
  }
}

// ---- k3_mfma: gathered FST GEMM, M=128 tile; plain stores to ypart ---------
// Block: 128 tokens x 128 cols x K=512 (8 steps of 64). 4 waves, M128xN32.
__global__ __launch_bounds__(256, 2) void k3_mfma(
    const _Float16* __restrict__ Fh, const _Float16* __restrict__ WhT,
    const float* __restrict__ fst_b, const int* __restrict__ cnt,
    const int* __restrict__ tlist, const float* __restrict__ wlist,
    const int* __restrict__ jobs, const int* __restrict__ njobs,
    float* __restrict__ ypart) {
  __shared__ _Float16 Bh[2][128 * 64];  // 32 KB
  __shared__ _Float16 Ah[2][128 * 64];  // 32 KB
  __shared__ int tl[128];
  __shared__ float wl[128];

  int tid = threadIdx.x;
  int job = blockIdx.x >> 2;
  int chunk = blockIdx.x & 3;
  if (job >= njobs[0]) return;
  int jb = jobs[job];
  int e = jb >> 8;
  int tile = jb & 255;
  int c0 = chunk * 128;
  int c_e = cnt[e];
  int t0 = tile * 128;

  if (tid < 128) {
    int t = t0 + tid;
    tl[tid] = tlist[e * B_N + (t < c_e ? t : t0)];
    wl[tid] = (t < c_e) ? wlist[e * B_N + t] : 0.0f;
  }
  __syncthreads();

  int wave = tid >> 6, lane = tid & 63;
  const _Float16* WhT_e = WhT + ((size_t)e << 18);

  size_t bsrc[4];
  int bdst[4];
  #pragma unroll
  for (int i = 0; i < 4; ++i) {
    int cw = wave * 32 + i * 8;
    int cl = cw + (lane >> 3);
    int g = (lane & 7) ^ (cl & 7);
    bsrc[i] = (size_t)(c0 + cl) * 512 + g * 8;
    bdst[i] = cw * 64;
  }
  size_t asrc[4];
  int adst[4];
  #pragma unroll
  for (int j = 0; j < 4; ++j) {
    int tw = wave * 32 + j * 8;
    int tkl = tw + (lane >> 3);
    int g = (lane & 7) ^ (tkl & 7);
    asrc[j] = (size_t)(tl[tkl] & 4095) * 512 + g * 8;
    adst[j] = tw * 64;
  }

  f32x4 acc[8][2];
  #pragma unroll
  for (int mt = 0; mt < 8; ++mt)
    #pragma unroll
    for (int ct = 0; ct < 2; ++ct) acc[mt][ct] = (f32x4){0.f, 0.f, 0.f, 0.f};

  int kg = lane >> 4;
  int mrow = lane & 15;

  #define STAGE(K0S, BUF)                                                     \
    do {                                                                      \
      _Pragma("unroll")                                                       \
      for (int i = 0; i < 4; ++i)                                             \
        GLL(WhT_e + bsrc[i] + (K0S), &Bh[BUF][0] + bdst[i]);                  \
      _Pragma("unroll")                                                       \
      for (int j = 0; j < 4; ++j)                                             \
        GLL(Fh + asrc[j] + (K0S), &Ah[BUF][0] + adst[j]);                     \
    } while (0)

  STAGE(0, 0);
  __syncthreads();

  int buf = 0;
  for (int s = 0; s < 8; ++s) {
    if (s < 7) STAGE((s + 1) * 64, buf ^ 1);  // issue next-step loads FIRST
    #pragma unroll
    for (int kh = 0; kh < 2; ++kh) {
      int gq = kh * 4 + kg;
      half8 bf[2];
      #pragma unroll
      for (int ct = 0; ct < 2; ++ct) {
        int cl = wave * 32 + ct * 16 + mrow;
        bf[ct] = *(const half8*)(&Bh[buf][0] + cl * 64 + ((gq ^ (cl & 7)) * 8));
      }
      #pragma unroll
      for (int mt = 0; mt < 8; ++mt) {
        int tr = mt * 16 + mrow;
        half8 af =
            *(const half8*)(&Ah[buf][0] + tr * 64 + ((gq ^ (tr & 7)) * 8));
        #pragma unroll
        for (int ct = 0; ct < 2; ++ct)
          acc[mt][ct] = __builtin_amdgcn_mfma_f32_16x16x32_f16(
              af, bf[ct], acc[mt][ct], 0, 0, 0);
      }
    }
    __syncthreads();
    buf ^= 1;
  }
  #undef STAGE

  // epilogue: plain stores, bias fused
  int rbase = (lane >> 4) * 4;
  int colbase = c0 + wave * 32 + mrow;
  float bia0 = fst_b[e * 512 + colbase];
  float bia1 = fst_b[e * 512 + colbase + 16];
  #pragma unroll
  for (int mt = 0; mt < 8; ++mt) {
    #pragma unroll
    for (int r = 0; r < 4; ++r) {
      int tloc = mt * 16 + rbase + r;
      float w = wl[tloc];
      if (w != 0.0f) {
        int v = tl[tloc];
        int tok = v & 4095;
        int slot = v >> 12;
        float* yp = ypart + (((size_t)tok * 8 + slot) << 9) + colbase;
        yp[0] = w * (acc[mt][0][r] + bia0);
        yp[16] = w * (acc[mt][1][r] + bia1);
      }
    }
  }
}

// ---- k4: out[b][f] = sum_s ypart[b][s][f] ----------------------------------
__global__ __launch_bounds__(256) void k4_reduce(const float* __restrict__ ypart,
                                                 float* __restrict__ out) {
  int b = blockIdx.x, tid = threadIdx.x;
  #pragma unroll
  for (int q = 0; q < 2; ++q) {
    int f = tid + q * 256;
    float a = 0.0f;
    #pragma unroll
    for (int s = 0; s < 8; ++s) a += ypart[(((size_t)b * 8 + s) << 9) + f];
    out[(size_t)b * 512 + f] = a;
  }
}

// ================= FP32 minimal fallback (tiny ws) ==========================
__global__ __launch_bounds__(64) void k0g(
    const float* __restrict__ pwT, const float* __restrict__ proj_b,
    const float* __restrict__ embT, const float* __restrict__ enT,
    float* __restrict__ Gpack, float* __restrict__ gbias) {
  __shared__ float row[256];
  int f = blockIdx.x;
  int e = threadIdx.x;
  const float* src = (f < 512) ? (pwT + f * 256) : proj_b;
  *(float4*)&row[e * 4] = *(const float4*)&src[e * 4];
  __syncthreads();
  float g = 0.0f;
  #pragma unroll 8
  for (int h = 0; h < 256; ++h) g = fmaf(row[h], embT[h * 64 + e], g);
  if (f < 512) {
    Gpack[(f * 64 + e) * 2 + 0] = g;
    Gpack[(f * 64 + e) * 2 + 1] = enT[f * 64 + e];
  } else {
    gbias[e] = g;
  }
}

__global__ __launch_bounds__(256) void k1_score(
    const float* __restrict__ features, const float* __restrict__ Gpack,
    const float* __restrict__ gbias, const float* __restrict__ coef,
    int* __restrict__ cnt, int* __restrict__ tk_idx, float* __restrict__ tk_w,
    int* __restrict__ tlist, float* __restrict__ wlist) {
  __shared__ float Ft[2][512];
  __shared__ float pl[4][64];
  __shared__ float ps[4][64];
  __shared__ float pn[4];
  int tid = threadIdx.x;
  int b0 = blockIdx.x * 2;
  {
    int t = tid >> 7;
    int fo = (tid & 127) * 4;
    *(float4*)&Ft[t][fo] =
        *(const float4*)&features[(size_t)(b0 + t) * 512 + fo];
  }
  __syncthreads();
  int wave = tid >> 6, e = tid & 63;
  int tok = wave & 1;
  int f0 = (wave >> 1) * 256;
  float la = 0.f, lb = 0.f, sa = 0.f, sb = 0.f;
  #pragma unroll 4
  for (int f = f0; f < f0 + 256; f += 2) {
    float2 g0 = *(const float2*)&Gpack[(f * 64 + e) * 2];
    float2 g1 = *(const float2*)&Gpack[((f + 1) * 64 + e) * 2];
    float x0 = Ft[tok][f];
    float x1 = Ft[tok][f + 1];
    la = fmaf(x0, g0.x, la);
    sa = fmaf(x0, g0.y, sa);
    lb = fmaf(x1, g1.x, lb);
    sb = fmaf(x1, g1.y, sb);
  }
  float nn = 0.f;
  #pragma unroll
  for (int j = 0; j < 4; ++j) {
    float v = Ft[tok][f0 + e + 64 * j];
    nn = fmaf(v, v, nn);
  }
  #pragma unroll
  for (int off = 32; off; off >>= 1) nn += __shfl_xor(nn, off);
  pl[wave][e] = la + lb;
  ps[wave][e] = sa + sb;
  if (e == 0) pn[wave] = nn;
  __syncthreads();
  if (wave < 2) {
    int b = b0 + wave;
    float l = pl[wave][e] + pl[wave + 2][e];
    float s = ps[wave][e] + ps[wave + 2][e];
    float ntot = pn[wave] + pn[wave + 2];
    float inv_n = 1.0f / fmaxf(sqrtf(ntot), 1e-8f);
    float gate = 1.0f / (1.0f + expf(-(l + gbias[e]) * 0.0625f));
    float sim = fmaxf(s * inv_n, 0.0f);
    float score = gate * sim * coef[e];
    float cur = score;
    float bv[8];
    int bi[8];
    #pragma unroll
    for (int r = 0; r < 8; ++r) {
      float mv = cur;
      int mi = e;
      #pragma unroll
      for (int off = 1; off < 64; off <<= 1) {
        float ov = __shfl_xor(mv, off);
        int oi = __shfl_xor(mi, off);
        if (ov > mv || (ov == mv && oi < mi)) { mv = ov; mi = oi; }
      }
      bv[r] = mv;
      bi[r] = mi;
      if (e == mi) cur = -1.0f;
    }
    float m0 = bv[0];
    float ex[8];
    float sum = 0.0f;
    #pragma unroll
    for (int r = 0; r < 8; ++r) { ex[r] = expf(bv[r] - m0); sum += ex[r]; }
    float isum = 1.0f / sum;
    if (e < 8) {
      int ir = 0; float er = 0.0f;
      switch (e) {
        case 0: ir = bi[0]; er = ex[0]; break;
        case 1: ir = bi[1]; er = ex[1]; break;
        case 2: ir = bi[2]; er = ex[2]; break;
        case 3: ir = bi[3]; er = ex[3]; break;
        case 4: ir = bi[4]; er = ex[4]; break;
        case 5: ir = bi[5]; er = ex[5]; break;
        case 6: ir = bi[6]; er = ex[6]; break;
        case 7: ir = bi[7]; er = ex[7]; break;
      }
      float wr = er * isum;
      int pos = atomicAdd(&cnt[ir], 1);
      tlist[ir * B_N + pos] = b;
      wlist[ir * B_N + pos] = wr;
      tk_idx[b * 8 + e] = ir;
      tk_w[b * 8 + e] = wr;
    }
  }
}

__global__ __launch_bounds__(256) void k2_bias(
    const int* __restrict__ tk_idx, const float* __restrict__ tk_w,
    const float* __restrict__ fst_b, float* __restrict__ out) {
  int b = blockIdx.x, tid = threadIdx.x;
  int ir[8];
  float wr[8];
  #pragma unroll
  for (int r = 0; r < 8; ++r) {
    ir[r] = tk_idx[b * 8 + r];
    wr[r] = tk_w[b * 8 + r];
  }
  #pragma unroll
  for (int q = 0; q < 2; ++q) {
    int f = tid + q * 256;
    float a = 0.0f;
    #pragma unroll
    for (int r = 0; r < 8; ++r) a = fmaf(wr[r], fst_b[ir[r] * 512 + f], a);
    out[(size_t)b * 512 + f] = a;
  }
}

#define TM 64
#define TN 256
#define KC 16
__global__ __launch_bounds__(256, 2) void k3_fst(
    const float* __restrict__ features, const float* __restrict__ fst_w,
    const int* __restrict__ cnt, const int* __restrict__ tlist,
    const float* __restrict__ wlist, float* __restrict__ out) {
  __shared__ float Ws[2][KC][TN];
  __shared__ float Ft[2][KC][TM];
  __shared__ int tl[TM];
  __shared__ float wl[TM];
  int tid = threadIdx.x;
  int e = blockIdx.x & 63;
  int rest = blockIdx.x >> 6;
  int tile = rest >> 1;
  int ch = rest & 1;
  int c0 = ch * TN;
  int c_e = cnt[e];
  int t0 = tile * TM;
  if (t0 >= c_e) return;
  if (tid < TM) {
    int t = t0 + tid;
    if (t < c_e) {
      tl[tid] = tlist[e * B_N + t] & 4095;
      wl[tid] = wlist[e * B_N + t];
    } else {
      tl[tid] = tlist[e * B_N + t0] & 4095;
      wl[tid] = 0.0f;
    }
  }
  __syncthreads();
  const float* fw_e = fst_w + (size_t)e * (512 * 512);
  int wave = tid >> 6, lane = tid & 63;
  int tg = wave * 2 + (lane >> 5);
  int cg = lane & 31;
  int ft_t = tid >> 2;
  int ft_fq = tid & 3;
  const float* ft_src_row = features + (size_t)tl[ft_t] * 512;
  auto stageWs = [&](int kc, int buf) {
    int f0 = kc * KC;
    #pragma unroll
    for (int r = 0; r < 4; ++r) {
      int f = wave * 4 + r;
      const float* src = fw_e + (size_t)(f0 + f) * 512 + c0 + lane * 4;
      GLL(src, &Ws[buf][f][0]);
    }
  };
  auto loadFt = [&](int kc) -> float4 {
    return *(const float4*)&ft_src_row[kc * KC + ft_fq * 4];
  };
  auto writeFt = [&](float4 v, int buf) {
    Ft[buf][ft_fq * 4 + 0][ft_t] = v.x;
    Ft[buf][ft_fq * 4 + 1][ft_t] = v.y;
    Ft[buf][ft_fq * 4 + 2][ft_t] = v.z;
    Ft[buf][ft_fq * 4 + 3][ft_t] = v.w;
  };
  float acc[8][8];
  #pragma unroll
  for (int j = 0; j < 8; ++j)
    #pragma unroll
    for (int i = 0; i < 8; ++i) acc[j][i] = 0.0f;
  auto compute = [&](int buf) {
    #pragma unroll 4
    for (int f = 0; f < KC; ++f) {
      float4 a0 = *(const float4*)&Ft[buf][f][tg * 8];
      float4 a1 = *(const float4*)&Ft[buf][f][tg * 8 + 4];
      float4 w0 = *(const float4*)&Ws[buf][f][cg * 4];
      float4 w1 = *(const float4*)&Ws[buf][f][cg * 4 + 128];
      float av[8] = {a0.x, a0.y, a0.z, a0.w, a1.x, a1.y, a1.z, a1.w};
      float wv[8] = {w0.x, w0.y, w0.z, w0.w, w1.x, w1.y, w1.z, w1.w};
      #pragma unroll
      for (int j = 0; j < 8; ++j)
        #pragma unroll
        for (int i = 0; i < 8; ++i)
          acc[j][i] = fmaf(av[j], wv[i], acc[j][i]);
    }
  };
  stageWs(0, 0);
  float4 rf = loadFt(0);
  writeFt(rf, 0);
  __syncthreads();
  for (int kc = 0; kc < 32; ++kc) {
    int cb = kc & 1, nb = cb ^ 1;
    float4 rn = make_float4(0.f, 0.f, 0.f, 0.f);
    if (kc < 31) {
      stageWs(kc + 1, nb);
      rn = loadFt(kc + 1);
    }
    compute(cb);
    if (kc < 31) writeFt(rn, nb);
    __syncthreads();
  }
  #pragma unroll
  for (int j = 0; j < 8; ++j) {
    int lt = tg * 8 + j;
    float w = wl[lt];
    if (w != 0.0f) {
      size_t orow = (size_t)tl[lt] * 512 + c0 + cg * 4;
      #pragma unroll
      for (int i = 0; i < 4; ++i) atomicAdd(&out[orow + i], w * acc[j][i]);
      #pragma unroll
      for (int i = 0; i < 4; ++i)
        atomicAdd(&out[orow + 128 + i], w * acc[j][i + 4]);
    }
  }
}

// ---------------- launch ----------------------------------------------------
extern "C" void kernel_launch(void* const* d_in, const int* in_sizes, int n_in,
                              void* d_out, int out_size, void* d_ws,
                              size_t ws_size, hipStream_t stream) {
  const float* features = (const float*)d_in[0];
  const float* proj_w = (const float*)d_in[1];
  const float* proj_b = (const float*)d_in[2];
  const float* expert_emb = (const float*)d_in[3];
  const float* expert_features = (const float*)d_in[4];
  const float* trust = (const float*)d_in[5];
  const float* dt = (const float*)d_in[6];
  const float* fst_w = (const float*)d_in[7];
  const float* fst_b = (const float*)d_in[8];
  float* out = (float*)d_out;
  float* ws = (float*)d_ws;

  float* coef = ws;                          // 64
  int* cnt = (int*)(ws + 64);                // 64
  float* gbias = ws + 128;                   // 64
  int* njobs = (int*)(ws + 192);             // 64
  int* jobs = (int*)(ws + 256);              // 2048
  int* tlist = (int*)(ws + 2304);            // 64*2048
  float* wlist = ws + 133376;                // 64*2048
  _Float16* Fh = (_Float16*)(ws + 264448);   // 2048*512 halfs
  _Float16* WhT = (_Float16*)(ws + 788736);  // 64*512*512 halfs
  float* U = ws + 9177344;                   // union region
  float* pwT = U;                            // 512*256 (pre-k3 only)
  float* embT = U + 131072;                  // 256*64
  float* enT = U + 147456;                   // 512*64
  _Float16* Fl = (_Float16*)(U + 180224);    // 2048*512 halfs
  _Float16* GhT = (_Float16*)(U + 704512);   // 128*512 halfs
  _Float16* GlT = (_Float16*)(U + 737280);   // 128*512 halfs
  float* fnorm = U + 770048;                 // 2048
  float* scores4 = U + 772096;               // 4*2048*128
  int* sel = (int*)(U + 1820672);            // 2048*8
  float* selw = U + 1837056;                 // 2048*8
  float* ypart = U;                          // 2048*8*512 (clobbers U post-sel)
  size_t need3 = (size_t)(9177344 + 8388608) * 4;

  if (ws_size >= need3) {
    hipLaunchKernelGGL(k_prep, dim3(2112), dim3(256), 0, stream, proj_w,
                       expert_emb, expert_features, trust, dt, features, fst_w,
                       pwT, embT, enT, coef, cnt, Fh, Fl, fnorm, WhT, njobs);
    hipLaunchKernelGGL(k0gs, dim3(513), dim3(64), 0, stream, pwT, proj_b,
                       embT, enT, GhT, GlT, gbias);
    hipLaunchKernelGGL(k1a_mfma, dim3(256), dim3(256), 0, stream, Fh, Fl, GhT,
                       GlT, scores4);
    hipLaunchKernelGGL(k1b_rank, dim3(512), dim3(256), 0, stream, scores4,
                       fnorm, coef, gbias, sel, selw);
    hipLaunchKernelGGL(k_gather, dim3(64), dim3(256), 0, stream, sel, selw,
                       cnt, tlist, wlist, jobs, njobs);
    hipLaunchKernelGGL(k3_mfma, dim3(2048), dim3(256), 0, stream, Fh, WhT,
                       fst_b, cnt, tlist, wlist, jobs, njobs, ypart);
    hipLaunchKernelGGL(k4_reduce, dim3(2048), dim3(256), 0, stream, ypart,
                       out);
  } else {
    float* pwT2 = ws;
    float* embT2 = pwT2 + 131072;
    float* enT2 = embT2 + 16384;
    float* coef2 = enT2 + 32768;
    int* cnt2 = (int*)(coef2 + 64);
    int* tk_idx = cnt2 + 64;
    float* tk_w = (float*)(tk_idx + 16384);
    int* tlist2 = (int*)(tk_w + 16384);
    float* wlist2 = (float*)(tlist2 + 131072);
    float* Gpack = wlist2 + 131072;
    float* gbias2 = Gpack + 65536;
    hipLaunchKernelGGL(k_prep, dim3(576), dim3(256), 0, stream, proj_w,
                       expert_emb, expert_features, trust, dt, features, fst_w,
                       pwT2, embT2, enT2, coef2, cnt2, (_Float16*)Gpack,
                       (_Float16*)Gpack, Gpack, (_Float16*)Gpack,
                       (int*)(gbias2 + 64));
    hipLaunchKernelGGL(k0g, dim3(513), dim3(64), 0, stream, pwT2, proj_b,
                       embT2, enT2, Gpack, gbias2);
    hipLaunchKernelGGL(k1_score, dim3(1024), dim3(256), 0, stream, features,
                       Gpack, gbias2, coef2, cnt2, tk_idx, tk_w, tlist2,
                       wlist2);
    hipLaunchKernelGGL(k2_bias, dim3(2048), dim3(256), 0, stream, tk_idx,
                       tk_w, fst_b, out);
    hipLaunchKernelGGL(k3_fst, dim3(4096), dim3(256), 0, stream, features,
                       fst_w, cnt2, tlist2, wlist2, out);
  }
}

// Round 14
// 101.600 us; speedup vs baseline: 4.5144x; 1.0579x over previous
//
#include <hip/hip_runtime.h>
#include <hip/hip_fp16.h>
#include <math.h>

#define B_N 2048
#define F_N 512
#define H_N 256
#define E_N 64

typedef __attribute__((ext_vector_type(8))) _Float16 half8;
typedef __attribute__((ext_vector_type(4))) float f32x4;

#define GLL(srcp, dstp)                                                       \
  __builtin_amdgcn_global_load_lds(                                           \
      (const __attribute__((address_space(1))) void*)(srcp),                  \
      (__attribute__((address_space(3))) void*)(dstp), 16, 0, 0)

// ================= MAIN PATH (7 kernels) ====================================

// ---- k_prep: fused input transforms. grid 2112 (main) or 576 (fallback).
__global__ __launch_bounds__(256) void k_prep(
    const float* __restrict__ proj_w, const float* __restrict__ expert_emb,
    const float* __restrict__ expert_features, const float* __restrict__ trust,
    const float* __restrict__ dt, const float* __restrict__ features,
    const float* __restrict__ fst_w, float* __restrict__ pwT,
    float* __restrict__ embT, float* __restrict__ enT,
    float* __restrict__ coef, int* __restrict__ cnt, _Float16* __restrict__ Fh,
    _Float16* __restrict__ Fl, float* __restrict__ fnorm,
    _Float16* __restrict__ WhT, int* __restrict__ njobs) {
  __shared__ float tile[16704];
  __shared__ float parts[4];
  int bid = blockIdx.x, tid = threadIdx.x;
  if (bid < 512) {
    int idx = bid * 256 + tid;
    int f = idx >> 8, h = idx & 255;
    pwT[idx] = proj_w[h * 512 + f];
    if (bid == 0 && tid < E_N) cnt[tid] = 0;
    if (bid == 0 && tid == 64) njobs[0] = 0;
  } else if (bid < 576) {
    int e = bid - 512;  // 0..63
    float v0 = expert_features[e * 512 + tid];
    float v1 = expert_features[e * 512 + tid + 256];
    float ss = v0 * v0 + v1 * v1;
    #pragma unroll
    for (int off = 32; off; off >>= 1) ss += __shfl_xor(ss, off);
    if ((tid & 63) == 0) parts[tid >> 6] = ss;
    __syncthreads();
    float tot = parts[0] + parts[1] + parts[2] + parts[3];
    float inv = 1.0f / fmaxf(sqrtf(tot), 1e-8f);
    enT[tid * 64 + e] = v0 * inv;
    enT[(tid + 256) * 64 + e] = v1 * inv;
    embT[tid * 64 + e] = expert_emb[e * 256 + tid];
    if (tid == 0) {
      float st = fmaxf(0.1f, expf(-0.005f * dt[e]));
      coef[e] = trust[e] * st;
    }
  } else if (bid < 1088) {
    // convF: fp16 hi + scaled lo + row norms
    int gid = (bid - 576) * 256 + tid;
    int i = gid * 8;
    float4 v0 = *(const float4*)(features + i);
    float4 v1 = *(const float4*)(features + i + 4);
    float xs[8] = {v0.x, v0.y, v0.z, v0.w, v1.x, v1.y, v1.z, v1.w};
    half8 h, l;
    float ss = 0.0f;
    #pragma unroll
    for (int j = 0; j < 8; ++j) {
      h[j] = (_Float16)xs[j];
      l[j] = (_Float16)((xs[j] - (float)h[j]) * 2048.0f);
      ss = fmaf(xs[j], xs[j], ss);
    }
    *(half8*)(Fh + i) = h;
    *(half8*)(Fl + i) = l;
    #pragma unroll
    for (int off = 32; off; off >>= 1) ss += __shfl_xor(ss, off);
    if ((tid & 63) == 0) fnorm[gid >> 6] = ss;
  } else {
    // convW: fst_w -> transposed fp16 [e][col][k]
    int b2 = bid - 1088;  // 1024 = 64e x 8kb x 2cb
    int e = b2 >> 4;
    int kb = (b2 >> 1) & 7;
    int cb = b2 & 1;
    const float* src = fst_w + ((size_t)e << 18) + (size_t)(kb * 64) * 512 +
                       cb * 256;
    int kr = tid >> 6;
    int c4 = (tid & 63) * 4;
    #pragma unroll
    for (int r = 0; r < 16; ++r) {
      int k = r * 4 + kr;
      *(float4*)&tile[k * 260 + ((k >> 3) << 2) + c4] =
          *(const float4*)&src[(size_t)k * 512 + c4];
    }
    __syncthreads();
    int co = tid >> 3;
    int ko = (tid & 7) * 8;
    #pragma unroll
    for (int g = 0; g < 8; ++g) {
      int c = g * 32 + co;
      half8 vh;
      #pragma unroll
      for (int i = 0; i < 8; ++i) {
        int k = ko + i;
        vh[i] = (_Float16)tile[k * 260 + ((k >> 3) << 2) + c];
      }
      size_t dbase =
          ((size_t)e << 18) + (size_t)(cb * 256 + c) * 512 + kb * 64 + ko;
      *(half8*)(WhT + dbase) = vh;
    }
  }
}

// ---- k0gs: gate matrix + enT -> fp16 2-term GhT/GlT [128 col][512 k]; gbias
__global__ __launch_bounds__(64) void k0gs(
    const float* __restrict__ pwT, const float* __restrict__ proj_b,
    const float* __restrict__ embT, const float* __restrict__ enT,
    _Float16* __restrict__ GhT, _Float16* __restrict__ GlT,
    float* __restrict__ gbias) {
  __shared__ float row[256];
  int f = blockIdx.x;
  int e = threadIdx.x;
  const float* src = (f < 512) ? (pwT + f * 256) : proj_b;
  *(float4*)&row[e * 4] = *(const float4*)&src[e * 4];
  __syncthreads();
  float g = 0.0f;
  #pragma unroll 8
  for (int h = 0; h < 256; ++h) g = fmaf(row[h], embT[h * 64 + e], g);
  if (f < 512) {
    _Float16 h0 = (_Float16)g;
    GhT[e * 512 + f] = h0;
    GlT[e * 512 + f] = (_Float16)((g - (float)h0) * 2048.0f);
    float en = enT[f * 64 + e];
    _Float16 h1 = (_Float16)en;
    GhT[(64 + e) * 512 + f] = h1;
    GlT[(64 + e) * 512 + f] = (_Float16)((en - (float)h1) * 2048.0f);
  } else {
    gbias[e] = g;
  }
}

// ---- k1a: scoring GEMM via MFMA, fp16 2-term, K-split 4 --------------------
__global__ __launch_bounds__(256, 2) void k1a_mfma(
    const _Float16* __restrict__ Fh, const _Float16* __restrict__ Fl,
    const _Float16* __restrict__ GhT, const _Float16* __restrict__ GlT,
    float* __restrict__ scores4) {
  __shared__ _Float16 Bh[2][128 * 64];
  __shared__ _Float16 Bl[2][128 * 64];
  __shared__ _Float16 Ah[2][32 * 64];
  __shared__ _Float16 Al[2][32 * 64];
  int tid = threadIdx.x;
  int kc = blockIdx.x & 3;
  int tt = blockIdx.x >> 2;
  int b0 = tt * 32;
  int k0 = kc * 128;
  int wave = tid >> 6, lane = tid & 63;
  size_t bsrc[4];
  int bdst[4];
  #pragma unroll
  for (int i = 0; i < 4; ++i) {
    int cw = wave * 32 + i * 8;
    int cl = cw + (lane >> 3);
    int g = (lane & 7) ^ (cl & 7);
    bsrc[i] = (size_t)cl * 512 + k0 + g * 8;
    bdst[i] = cw * 64;
  }
  int tw = wave * 8;
  int tkl = tw + (lane >> 3);
  int ga = (lane & 7) ^ (tkl & 7);
  size_t asrc = (size_t)(b0 + tkl) * 512 + k0 + ga * 8;
  int adst = tw * 64;
  f32x4 accH[2][2], accM[2][2];
  #pragma unroll
  for (int mt = 0; mt < 2; ++mt)
    #pragma unroll
    for (int ct = 0; ct < 2; ++ct) {
      accH[mt][ct] = (f32x4){0.f, 0.f, 0.f, 0.f};
      accM[mt][ct] = (f32x4){0.f, 0.f, 0.f, 0.f};
    }
  int kg = lane >> 4;
  int mrow = lane & 15;
  #define STG(K0S, BUF)                                                       \
    do {                                                                      \
      _Pragma("unroll")                                                       \
      for (int i = 0; i < 4; ++i) {                                           \
        GLL(GhT + bsrc[i] + (K0S), &Bh[BUF][0] + bdst[i]);                    \
        GLL(GlT + bsrc[i] + (K0S), &Bl[BUF][0] + bdst[i]);                    \
      }                                                                       \
      GLL(Fh + asrc + (K0S), &Ah[BUF][0] + adst);                             \
      GLL(Fl + asrc + (K0S), &Al[BUF][0] + adst);                             \
    } while (0)
  STG(0, 0);
  __syncthreads();
  int buf = 0;
  #pragma unroll
  for (int s = 0; s < 2; ++s) {
    if (s < 1) STG(64, 1);
    #pragma unroll
    for (int kh = 0; kh < 2; ++kh) {
      int gq = kh * 4 + kg;
      half8 afh[2], afl[2], bfh[2], bfl[2];
      #pragma unroll
      for (int mt = 0; mt < 2; ++mt) {
        int tr = mt * 16 + mrow;
        int off = tr * 64 + ((gq ^ (tr & 7)) * 8);
        afh[mt] = *(const half8*)(&Ah[buf][0] + off);
        afl[mt] = *(const half8*)(&Al[buf][0] + off);
      }
      #pragma unroll
      for (int ct = 0; ct < 2; ++ct) {
        int cl = wave * 32 + ct * 16 + mrow;
        int off = cl * 64 + ((gq ^ (cl & 7)) * 8);
        bfh[ct] = *(const half8*)(&Bh[buf][0] + off);
        bfl[ct] = *(const half8*)(&Bl[buf][0] + off);
      }
      #pragma unroll
      for (int mt = 0; mt < 2; ++mt)
        #pragma unroll
        for (int ct = 0; ct < 2; ++ct) {
          accH[mt][ct] = __builtin_amdgcn_mfma_f32_16x16x32_f16(
              afh[mt], bfh[ct], accH[mt][ct], 0, 0, 0);
          accM[mt][ct] = __builtin_amdgcn_mfma_f32_16x16x32_f16(
              afh[mt], bfl[ct], accM[mt][ct], 0, 0, 0);
          accM[mt][ct] = __builtin_amdgcn_mfma_f32_16x16x32_f16(
              afl[mt], bfh[ct], accM[mt][ct], 0, 0, 0);
        }
    }
    __syncthreads();
    buf ^= 1;
  }
  #undef STG
  int rbase = (lane >> 4) * 4;
  #pragma unroll
  for (int mt = 0; mt < 2; ++mt)
    #pragma unroll
    for (int ct = 0; ct < 2; ++ct)
      #pragma unroll
      for (int r = 0; r < 4; ++r) {
        int tok = b0 + mt * 16 + rbase + r;
        int col = wave * 32 + ct * 16 + mrow;
        scores4[((size_t)(kc * 2048 + tok) << 7) + col] =
            accH[mt][ct][r] + accM[mt][ct][r] * (1.0f / 2048.0f);
      }
}

// ---- k1b: rank-based top-8 (no butterfly, no global atomics) ---------------
__global__ __launch_bounds__(256) void k1b_rank(
    const float* __restrict__ scores4, const float* __restrict__ fnorm,
    const float* __restrict__ coef, const float* __restrict__ gbias,
    int* __restrict__ sel, float* __restrict__ selw) {
  __shared__ float sc[4][64];
  __shared__ float ex8[4][8];
  int tid = threadIdx.x;
  int wave = tid >> 6, lane = tid & 63;
  int b = blockIdx.x * 4 + wave;
  float l = 0.f, s = 0.f;
  #pragma unroll
  for (int kc = 0; kc < 4; ++kc) {
    const float* row = scores4 + ((size_t)(kc * 2048 + b) << 7);
    l += row[lane];
    s += row[64 + lane];
  }
  float inv_n = 1.0f / fmaxf(sqrtf(fnorm[b]), 1e-8f);
  float gate = 1.0f / (1.0f + expf(-(l + gbias[lane]) * 0.0625f));
  float sim = fmaxf(s * inv_n, 0.0f);
  float score = gate * sim * coef[lane];
  sc[wave][lane] = score;
  int rank = 0;
  float mx = score;
  #pragma unroll 8
  for (int j = 0; j < 64; ++j) {
    float sj = sc[wave][j];
    rank += (sj > score || (sj == score && j < lane)) ? 1 : 0;
    mx = fmaxf(mx, sj);
  }
  float ev = expf(score - mx);
  if (rank < 8) ex8[wave][rank] = ev;
  float sum = 0.f;
  #pragma unroll
  for (int r = 0; r < 8; ++r) sum += ex8[wave][r];
  if (rank < 8) {
    sel[b * 8 + rank] = lane;
    selw[b * 8 + rank] = ev / sum;
  }
}

// ---- k_gather: per-expert compaction (LDS atomics) + jobs (1 atomic/expert)
__global__ __launch_bounds__(256) void k_gather(
    const int* __restrict__ sel, const float* __restrict__ selw,
    int* __restrict__ cnt, int* __restrict__ tlist, float* __restrict__ wlist,
    int* __restrict__ jobs, int* __restrict__ njobs) {
  __shared__ int lcnt;
  int e = blockIdx.x;
  int tid = threadIdx.x;
  if (tid == 0) lcnt = 0;
  __syncthreads();
  for (int q = 0; q < 64; ++q) {
    int i = q * 256 + tid;
    if (sel[i] == e) {
      int pos = atomicAdd(&lcnt, 1);
      tlist[e * B_N + pos] = (i >> 3) | ((i & 7) << 12);  // token | slot<<12
      wlist[e * B_N + pos] = selw[i];
    }
  }
  __syncthreads();
  if (tid == 0) {
    int c = lcnt;
    cnt[e] = c;
    int nt = (c + 63) >> 6;  // 64-token tiles
    int base = atomicAdd(njobs, nt);
    for (int t = 0; t < nt; ++t) jobs[base + t] = (e << 8) | t;
  }
}

// ---- k3_mfma: gathered FST GEMM, M=64; plain stores (bias fused) to ypart --
__global__ __launch_bounds__(256, 3) void k3_mfma(
    const _Float16* __restrict__ Fh, const _Float16* __restrict__ WhT,
    const float* __restrict__ fst_b, const int* __restrict__ cnt,
    const int* __restrict__ tlist, const float* __restrict__ wlist,
    const int* __restrict__ jobs, const int* __restrict__ njobs,
    float* __restrict__ ypart) {
  __shared__ _Float16 Bh[2][128 * 64];  // 32 KB
  __shared__ _Float16 Ah[2][64 * 64];   // 16 KB
  __shared__ int tl[64];
  __shared__ float wl[64];

  int tid = threadIdx.x;
  int job = blockIdx.x >> 2;
  int chunk = blockIdx.x & 3;
  if (job >= njobs[0]) return;
  int jb = jobs[job];
  int e = jb >> 8;
  int tile = jb & 255;
  int c0 = chunk * 128;
  int c_e = cnt[e];
  int t0 = tile * 64;

  if (tid < 64) {
    int t = t0 + tid;
    tl[tid] = tlist[e * B_N + (t < c_e ? t : t0)];
    wl[tid] = (t < c_e) ? wlist[e * B_N + t] : 0.0f;
  }
  __syncthreads();

  int wave = tid >> 6, lane = tid & 63;
  const _Float16* WhT_e = WhT + ((size_t)e << 18);

  size_t bsrc[4];
  int bdst[4];
  #pragma unroll
  for (int i = 0; i < 4; ++i) {
    int cw = wave * 32 + i * 8;
    int cl = cw + (lane >> 3);
    int g = (lane & 7) ^ (cl & 7);
    bsrc[i] = (size_t)(c0 + cl) * 512 + g * 8;
    bdst[i] = cw * 64;
  }
  size_t asrc[2];
  int adst[2];
  #pragma unroll
  for (int j = 0; j < 2; ++j) {
    int tw = wave * 16 + j * 8;
    int tkl = tw + (lane >> 3);
    int g = (lane & 7) ^ (tkl & 7);
    asrc[j] = (size_t)(tl[tkl] & 4095) * 512 + g * 8;
    adst[j] = tw * 64;
  }

  f32x4 acc[4][2];
  #pragma unroll
  for (int mt = 0; mt < 4; ++mt)
    #pragma unroll
    for (int ct = 0; ct < 2; ++ct) acc[mt][ct] = (f32x4){0.f, 0.f, 0.f, 0.f};

  int kg = lane >> 4;
  int mrow = lane & 15;

  #define STAGE(K0S, BUF)                                                     \
    do {                                                                      \
      _Pragma("unroll")                                                       \
      for (int i = 0; i < 4; ++i)                                             \
        GLL(WhT_e + bsrc[i] + (K0S), &Bh[BUF][0] + bdst[i]);                  \
      _Pragma("unroll")                                                       \
      for (int j = 0; j < 2; ++j)                                             \
        GLL(Fh + asrc[j] + (K0S), &Ah[BUF][0] + adst[j]);                     \
    } while (0)

  STAGE(0, 0);
  __syncthreads();

  int buf = 0;
  for (int s = 0; s < 8; ++s) {
    if (s < 7) STAGE((s + 1) * 64, buf ^ 1);  // issue next-step loads FIRST
    #pragma unroll
    for (int kh = 0; kh < 2; ++kh) {
      int gq = kh * 4 + kg;
      half8 af[4], bf[2];
      #pragma unroll
      for (int mt = 0; mt < 4; ++mt) {
        int tr = mt * 16 + mrow;
        af[mt] = *(const half8*)(&Ah[buf][0] + tr * 64 + ((gq ^ (tr & 7)) * 8));
      }
      #pragma unroll
      for (int ct = 0; ct < 2; ++ct) {
        int cl = wave * 32 + ct * 16 + mrow;
        bf[ct] = *(const half8*)(&Bh[buf][0] + cl * 64 + ((gq ^ (cl & 7)) * 8));
      }
      #pragma unroll
      for (int mt = 0; mt < 4; ++mt)
        #pragma unroll
        for (int ct = 0; ct < 2; ++ct)
          acc[mt][ct] = __builtin_amdgcn_mfma_f32_16x16x32_f16(
              af[mt], bf[ct], acc[mt][ct], 0, 0, 0);
    }
    __syncthreads();
    buf ^= 1;
  }
  #undef STAGE

  int rbase = (lane >> 4) * 4;
  int colbase = c0 + wave * 32 + mrow;
  float bia0 = fst_b[e * 512 + colbase];
  float bia1 = fst_b[e * 512 + colbase + 16];
  #pragma unroll
  for (int mt = 0; mt < 4; ++mt) {
    #pragma unroll
    for (int r = 0; r < 4; ++r) {
      int tloc = mt * 16 + rbase + r;
      float w = wl[tloc];
      if (w != 0.0f) {
        int v = tl[tloc];
        int tok = v & 4095;
        int slot = v >> 12;
        float* yp = ypart + (((size_t)tok * 8 + slot) << 9) + colbase;
        yp[0] = w * (acc[mt][0][r] + bia0);
        yp[16] = w * (acc[mt][1][r] + bia1);
      }
    }
  }
}

// ---- k4: out[b][f] = sum_s ypart[b][s][f] ----------------------------------
__global__ __launch_bounds__(256) void k4_reduce(const float* __restrict__ ypart,
                                                 float* __restrict__ out) {
  int b = blockIdx.x, tid = threadIdx.x;
  #pragma unroll
  for (int q = 0; q < 2; ++q) {
    int f = tid + q * 256;
    float a = 0.0f;
    #pragma unroll
    for (int s = 0; s < 8; ++s) a += ypart[(((size_t)b * 8 + s) << 9) + f];
    out[(size_t)b * 512 + f] = a;
  }
}

// ================= FP32 minimal fallback (tiny ws) ==========================
__global__ __launch_bounds__(64) void k0g(
    const float* __restrict__ pwT, const float* __restrict__ proj_b,
    const float* __restrict__ embT, const float* __restrict__ enT,
    float* __restrict__ Gpack, float* __restrict__ gbias) {
  __shared__ float row[256];
  int f = blockIdx.x;
  int e = threadIdx.x;
  const float* src = (f < 512) ? (pwT + f * 256) : proj_b;
  *(float4*)&row[e * 4] = *(const float4*)&src[e * 4];
  __syncthreads();
  float g = 0.0f;
  #pragma unroll 8
  for (int h = 0; h < 256; ++h) g = fmaf(row[h], embT[h * 64 + e], g);
  if (f < 512) {
    Gpack[(f * 64 + e) * 2 + 0] = g;
    Gpack[(f * 64 + e) * 2 + 1] = enT[f * 64 + e];
  } else {
    gbias[e] = g;
  }
}

__global__ __launch_bounds__(256) void k1_score(
    const float* __restrict__ features, const float* __restrict__ Gpack,
    const float* __restrict__ gbias, const float* __restrict__ coef,
    int* __restrict__ cnt, int* __restrict__ tk_idx, float* __restrict__ tk_w,
    int* __restrict__ tlist, float* __restrict__ wlist) {
  __shared__ float Ft[2][512];
  __shared__ float pl[4][64];
  __shared__ float ps[4][64];
  __shared__ float pn[4];
  int tid = threadIdx.x;
  int b0 = blockIdx.x * 2;
  {
    int t = tid >> 7;
    int fo = (tid & 127) * 4;
    *(float4*)&Ft[t][fo] =
        *(const float4*)&features[(size_t)(b0 + t) * 512 + fo];
  }
  __syncthreads();
  int wave = tid >> 6, e = tid & 63;
  int tok = wave & 1;
  int f0 = (wave >> 1) * 256;
  float la = 0.f, lb = 0.f, sa = 0.f, sb = 0.f;
  #pragma unroll 4
  for (int f = f0; f < f0 + 256; f += 2) {
    float2 g0 = *(const float2*)&Gpack[(f * 64 + e) * 2];
    float2 g1 = *(const float2*)&Gpack[((f + 1) * 64 + e) * 2];
    float x0 = Ft[tok][f];
    float x1 = Ft[tok][f + 1];
    la = fmaf(x0, g0.x, la);
    sa = fmaf(x0, g0.y, sa);
    lb = fmaf(x1, g1.x, lb);
    sb = fmaf(x1, g1.y, sb);
  }
  float nn = 0.f;
  #pragma unroll
  for (int j = 0; j < 4; ++j) {
    float v = Ft[tok][f0 + e + 64 * j];
    nn = fmaf(v, v, nn);
  }
  #pragma unroll
  for (int off = 32; off; off >>= 1) nn += __shfl_xor(nn, off);
  pl[wave][e] = la + lb;
  ps[wave][e] = sa + sb;
  if (e == 0) pn[wave] = nn;
  __syncthreads();
  if (wave < 2) {
    int b = b0 + wave;
    float l = pl[wave][e] + pl[wave + 2][e];
    float s = ps[wave][e] + ps[wave + 2][e];
    float ntot = pn[wave] + pn[wave + 2];
    float inv_n = 1.0f / fmaxf(sqrtf(ntot), 1e-8f);
    float gate = 1.0f / (1.0f + expf(-(l + gbias[e]) * 0.0625f));
    float sim = fmaxf(s * inv_n, 0.0f);
    float score = gate * sim * coef[e];
    float cur = score;
    float bv[8];
    int bi[8];
    #pragma unroll
    for (int r = 0; r < 8; ++r) {
      float mv = cur;
      int mi = e;
      #pragma unroll
      for (int off = 1; off < 64; off <<= 1) {
        float ov = __shfl_xor(mv, off);
        int oi = __shfl_xor(mi, off);
        if (ov > mv || (ov == mv && oi < mi)) { mv = ov; mi = oi; }
      }
      bv[r] = mv;
      bi[r] = mi;
      if (e == mi) cur = -1.0f;
    }
    float m0 = bv[0];
    float ex[8];
    float sum = 0.0f;
    #pragma unroll
    for (int r = 0; r < 8; ++r) { ex[r] = expf(bv[r] - m0); sum += ex[r]; }
    float isum = 1.0f / sum;
    if (e < 8) {
      int ir = 0; float er = 0.0f;
      switch (e) {
        case 0: ir = bi[0]; er = ex[0]; break;
        case 1: ir = bi[1]; er = ex[1]; break;
        case 2: ir = bi[2]; er = ex[2]; break;
        case 3: ir = bi[3]; er = ex[3]; break;
        case 4: ir = bi[4]; er = ex[4]; break;
        case 5: ir = bi[5]; er = ex[5]; break;
        case 6: ir = bi[6]; er = ex[6]; break;
        case 7: ir = bi[7]; er = ex[7]; break;
      }
      float wr = er * isum;
      int pos = atomicAdd(&cnt[ir], 1);
      tlist[ir * B_N + pos] = b;
      wlist[ir * B_N + pos] = wr;
      tk_idx[b * 8 + e] = ir;
      tk_w[b * 8 + e] = wr;
    }
  }
}

__global__ __launch_bounds__(256) void k2_bias(
    const int* __restrict__ tk_idx, const float* __restrict__ tk_w,
    const float* __restrict__ fst_b, float* __restrict__ out) {
  int b = blockIdx.x, tid = threadIdx.x;
  int ir[8];
  float wr[8];
  #pragma unroll
  for (int r = 0; r < 8; ++r) {
    ir[r] = tk_idx[b * 8 + r];
    wr[r] = tk_w[b * 8 + r];
  }
  #pragma unroll
  for (int q = 0; q < 2; ++q) {
    int f = tid + q * 256;
    float a = 0.0f;
    #pragma unroll
    for (int r = 0; r < 8; ++r) a = fmaf(wr[r], fst_b[ir[r] * 512 + f], a);
    out[(size_t)b * 512 + f] = a;
  }
}

#define TM 64
#define TN 256
#define KC 16
__global__ __launch_bounds__(256, 2) void k3_fst(
    const float* __restrict__ features, const float* __restrict__ fst_w,
    const int* __restrict__ cnt, const int* __restrict__ tlist,
    const float* __restrict__ wlist, float* __restrict__ out) {
  __shared__ float Ws[2][KC][TN];
  __shared__ float Ft[2][KC][TM];
  __shared__ int tl[TM];
  __shared__ float wl[TM];
  int tid = threadIdx.x;
  int e = blockIdx.x & 63;
  int rest = blockIdx.x >> 6;
  int tile = rest >> 1;
  int ch = rest & 1;
  int c0 = ch * TN;
  int c_e = cnt[e];
  int t0 = tile * TM;
  if (t0 >= c_e) return;
  if (tid < TM) {
    int t = t0 + tid;
    if (t < c_e) {
      tl[tid] = tlist[e * B_N + t] & 4095;
      wl[tid] = wlist[e * B_N + t];
    } else {
      tl[tid] = tlist[e * B_N + t0] & 4095;
      wl[tid] = 0.0f;
    }
  }
  __syncthreads();
  const float* fw_e = fst_w + (size_t)e * (512 * 512);
  int wave = tid >> 6, lane = tid & 63;
  int tg = wave * 2 + (lane >> 5);
  int cg = lane & 31;
  int ft_t = tid >> 2;
  int ft_fq = tid & 3;
  const float* ft_src_row = features + (size_t)tl[ft_t] * 512;
  auto stageWs = [&](int kc, int buf) {
    int f0 = kc * KC;
    #pragma unroll
    for (int r = 0; r < 4; ++r) {
      int f = wave * 4 + r;
      const float* src = fw_e + (size_t)(f0 + f) * 512 + c0 + lane * 4;
      GLL(src, &Ws[buf][f][0]);
    }
  };
  auto loadFt = [&](int kc) -> float4 {
    return *(const float4*)&ft_src_row[kc * KC + ft_fq * 4];
  };
  auto writeFt = [&](float4 v, int buf) {
    Ft[buf][ft_fq * 4 + 0][ft_t] = v.x;
    Ft[buf][ft_fq * 4 + 1][ft_t] = v.y;
    Ft[buf][ft_fq * 4 + 2][ft_t] = v.z;
    Ft[buf][ft_fq * 4 + 3][ft_t] = v.w;
  };
  float acc[8][8];
  #pragma unroll
  for (int j = 0; j < 8; ++j)
    #pragma unroll
    for (int i = 0; i < 8; ++i) acc[j][i] = 0.0f;
  auto compute = [&](int buf) {
    #pragma unroll 4
    for (int f = 0; f < KC; ++f) {
      float4 a0 = *(const float4*)&Ft[buf][f][tg * 8];
      float4 a1 = *(const float4*)&Ft[buf][f][tg * 8 + 4];
      float4 w0 = *(const float4*)&Ws[buf][f][cg * 4];
      float4 w1 = *(const float4*)&Ws[buf][f][cg * 4 + 128];
      float av[8] = {a0.x, a0.y, a0.z, a0.w, a1.x, a1.y, a1.z, a1.w};
      float wv[8] = {w0.x, w0.y, w0.z, w0.w, w1.x, w1.y, w1.z, w1.w};
      #pragma unroll
      for (int j = 0; j < 8; ++j)
        #pragma unroll
        for (int i = 0; i < 8; ++i)
          acc[j][i] = fmaf(av[j], wv[i], acc[j][i]);
    }
  };
  stageWs(0, 0);
  float4 rf = loadFt(0);
  writeFt(rf, 0);
  __syncthreads();
  for (int kc = 0; kc < 32; ++kc) {
    int cb = kc & 1, nb = cb ^ 1;
    float4 rn = make_float4(0.f, 0.f, 0.f, 0.f);
    if (kc < 31) {
      stageWs(kc + 1, nb);
      rn = loadFt(kc + 1);
    }
    compute(cb);
    if (kc < 31) writeFt(rn, nb);
    __syncthreads();
  }
  #pragma unroll
  for (int j = 0; j < 8; ++j) {
    int lt = tg * 8 + j;
    float w = wl[lt];
    if (w != 0.0f) {
      size_t orow = (size_t)tl[lt] * 512 + c0 + cg * 4;
      #pragma unroll
      for (int i = 0; i < 4; ++i) atomicAdd(&out[orow + i], w * acc[j][i]);
      #pragma unroll
      for (int i = 0; i < 4; ++i)
        atomicAdd(&out[orow + 128 + i], w * acc[j][i + 4]);
    }
  }
}

// ---------------- launch ----------------------------------------------------
extern "C" void kernel_launch(void* const* d_in, const int* in_sizes, int n_in,
                              void* d_out, int out_size, void* d_ws,
                              size_t ws_size, hipStream_t stream) {
  const float* features = (const float*)d_in[0];
  const float* proj_w = (const float*)d_in[1];
  const float* proj_b = (const float*)d_in[2];
  const float* expert_emb = (const float*)d_in[3];
  const float* expert_features = (const float*)d_in[4];
  const float* trust = (const float*)d_in[5];
  const float* dt = (const float*)d_in[6];
  const float* fst_w = (const float*)d_in[7];
  const float* fst_b = (const float*)d_in[8];
  float* out = (float*)d_out;
  float* ws = (float*)d_ws;

  float* coef = ws;                          // 64
  int* cnt = (int*)(ws + 64);                // 64
  float* gbias = ws + 128;                   // 64
  int* njobs = (int*)(ws + 192);             // 64
  int* jobs = (int*)(ws + 256);              // 2048
  int* tlist = (int*)(ws + 2304);            // 64*2048
  float* wlist = ws + 133376;                // 64*2048
  _Float16* Fh = (_Float16*)(ws + 264448);   // 2048*512 halfs
  _Float16* WhT = (_Float16*)(ws + 788736);  // 64*512*512 halfs
  float* U = ws + 9177344;                   // union region
  float* pwT = U;                            // 512*256 (pre-k3 only)
  float* embT = U + 131072;                  // 256*64
  float* enT = U + 147456;                   // 512*64
  _Float16* Fl = (_Float16*)(U + 180224);    // 2048*512 halfs
  _Float16* GhT = (_Float16*)(U + 704512);   // 128*512 halfs
  _Float16* GlT = (_Float16*)(U + 737280);   // 128*512 halfs
  float* fnorm = U + 770048;                 // 2048
  float* scores4 = U + 772096;               // 4*2048*128
  int* sel = (int*)(U + 1820672);            // 2048*8
  float* selw = U + 1837056;                 // 2048*8
  float* ypart = U;                          // 2048*8*512 (clobbers U post-sel)
  size_t need3 = (size_t)(9177344 + 8388608) * 4;

  if (ws_size >= need3) {
    hipLaunchKernelGGL(k_prep, dim3(2112), dim3(256), 0, stream, proj_w,
                       expert_emb, expert_features, trust, dt, features, fst_w,
                       pwT, embT, enT, coef, cnt, Fh, Fl, fnorm, WhT, njobs);
    hipLaunchKernelGGL(k0gs, dim3(513), dim3(64), 0, stream, pwT, proj_b,
                       embT, enT, GhT, GlT, gbias);
    hipLaunchKernelGGL(k1a_mfma, dim3(256), dim3(256), 0, stream, Fh, Fl, GhT,
                       GlT, scores4);
    hipLaunchKernelGGL(k1b_rank, dim3(512), dim3(256), 0, stream, scores4,
                       fnorm, coef, gbias, sel, selw);
    hipLaunchKernelGGL(k_gather, dim3(64), dim3(256), 0, stream, sel, selw,
                       cnt, tlist, wlist, jobs, njobs);
    hipLaunchKernelGGL(k3_mfma, dim3(2048), dim3(256), 0, stream, Fh, WhT,
                       fst_b, cnt, tlist, wlist, jobs, njobs, ypart);
    hipLaunchKernelGGL(k4_reduce, dim3(2048), dim3(256), 0, stream, ypart,
                       out);
  } else {
    float* pwT2 = ws;
    float* embT2 = pwT2 + 131072;
    float* enT2 = embT2 + 16384;
    float* coef2 = enT2 + 32768;
    int* cnt2 = (int*)(coef2 + 64);
    int* tk_idx = cnt2 + 64;
    float* tk_w = (float*)(tk_idx + 16384);
    int* tlist2 = (int*)(tk_w + 16384);
    float* wlist2 = (float*)(tlist2 + 131072);
    float* Gpack = wlist2 + 131072;
    float* gbias2 = Gpack + 65536;
    hipLaunchKernelGGL(k_prep, dim3(576), dim3(256), 0, stream, proj_w,
                       expert_emb, expert_features, trust, dt, features, fst_w,
                       pwT2, embT2, enT2, coef2, cnt2, (_Float16*)Gpack,
                       (_Float16*)Gpack, Gpack, (_Float16*)Gpack,
                       (int*)(gbias2 + 64));
    hipLaunchKernelGGL(k0g, dim3(513), dim3(64), 0, stream, pwT2, proj_b,
                       embT2, enT2, Gpack, gbias2);
    hipLaunchKernelGGL(k1_score, dim3(1024), dim3(256), 0, stream, features,
                       Gpack, gbias2, coef2, cnt2, tk_idx, tk_w, tlist2,
                       wlist2);
    hipLaunchKernelGGL(k2_bias, dim3(2048), dim3(256), 0, stream, tk_idx,
                       tk_w, fst_b, out);
    hipLaunchKernelGGL(k3_fst, dim3(4096), dim3(256), 0, stream, features,
                       fst_w, cnt2, tlist2, wlist2, out);
  }
}